// Round 1
// baseline (587.220 us; speedup 1.0000x reference)
//
#include <hip/hip_runtime.h>
#include <math.h>

#define N_NODES 100000
#define E_EDGES 1600000
#define D_IN    128
#define H_MID   32
#define C_OUT   5

// ---------------- K1: xrel = x @ W_rel1 ; xroot = x @ W_root1 + b1 ----------
// 16 threads per node (each computes 4 of the 64 concatenated outputs).
__global__ __launch_bounds__(256) void k1_proj(
    const float* __restrict__ x,
    const float* __restrict__ Wrel,
    const float* __restrict__ Wroot,
    const float* __restrict__ b1,
    float* __restrict__ xrel,
    float* __restrict__ xroot) {
    int tid  = threadIdx.x;
    int node = blockIdx.x * 16 + (tid >> 4);
    int o4   = tid & 15;                 // which group of 4 outputs (0..15)
    bool isRel = (o4 < 8);
    int col  = isRel ? (o4 * 4) : ((o4 - 8) * 4);
    const float*  Wb   = (isRel ? Wrel : Wroot) + col;
    const float4* xrow = (const float4*)(x + (size_t)node * D_IN);

    float4 acc = make_float4(0.f, 0.f, 0.f, 0.f);
    #pragma unroll 8
    for (int k4 = 0; k4 < D_IN / 4; ++k4) {
        float4 xv = xrow[k4];
        const float* w0 = Wb + (k4 * 4) * H_MID;
        float4 wa = *(const float4*)(w0);
        float4 wb = *(const float4*)(w0 + H_MID);
        float4 wc = *(const float4*)(w0 + 2 * H_MID);
        float4 wd = *(const float4*)(w0 + 3 * H_MID);
        acc.x += xv.x * wa.x + xv.y * wb.x + xv.z * wc.x + xv.w * wd.x;
        acc.y += xv.x * wa.y + xv.y * wb.y + xv.z * wc.y + xv.w * wd.y;
        acc.z += xv.x * wa.z + xv.y * wb.z + xv.z * wc.z + xv.w * wd.z;
        acc.w += xv.x * wa.w + xv.y * wb.w + xv.z * wc.w + xv.w * wd.w;
    }
    if (isRel) {
        *(float4*)(xrel + (size_t)node * H_MID + col) = acc;
    } else {
        acc.x += b1[col + 0]; acc.y += b1[col + 1];
        acc.z += b1[col + 2]; acc.w += b1[col + 3];
        *(float4*)(xroot + (size_t)node * H_MID + col) = acc;
    }
}

// ---------------- K_zero: zero agg1 | cnt | agg2 (contiguous, 38*N floats) --
__global__ __launch_bounds__(256) void k_zero(float4* __restrict__ p, int n4) {
    int i = blockIdx.x * 256 + threadIdx.x;
    if (i < n4) p[i] = make_float4(0.f, 0.f, 0.f, 0.f);
}

// ---------------- K3: scatter layer-1 messages (32 lanes per edge) ----------
__global__ __launch_bounds__(256) void k3_scatter1(
    const int* __restrict__ src,
    const int* __restrict__ dst,
    const float* __restrict__ ew,
    const float* __restrict__ xrel,
    float* __restrict__ agg1,
    float* __restrict__ cnt) {
    int t = blockIdx.x * 256 + threadIdx.x;
    int e = t >> 5;
    int lane = t & 31;
    int s = src[e];
    int d = dst[e];
    float w = ew[e];
    float val = xrel[(size_t)s * H_MID + lane] * w;
    atomicAdd(&agg1[(size_t)d * H_MID + lane], val);
    if (lane == 0) atomicAdd(&cnt[d], 1.0f);
}

// ---------------- K4: h = relu(agg1/cnt + xroot); project to 5+5 ------------
__global__ __launch_bounds__(256) void k4_node(
    const float* __restrict__ agg1,
    const float* __restrict__ cnt,
    const float* __restrict__ xroot,
    const float* __restrict__ Wrel2,
    const float* __restrict__ Wroot2,
    const float* __restrict__ b2,
    float* __restrict__ h2rel,
    float* __restrict__ h2root) {
    int n = blockIdx.x * 256 + threadIdx.x;
    if (n >= N_NODES) return;
    float inv = 1.0f / fmaxf(cnt[n], 1.0f);
    const float4* ar = (const float4*)(agg1  + (size_t)n * H_MID);
    const float4* xr = (const float4*)(xroot + (size_t)n * H_MID);
    float h[H_MID];
    #pragma unroll
    for (int i = 0; i < H_MID / 4; ++i) {
        float4 a = ar[i];
        float4 r = xr[i];
        h[4 * i + 0] = fmaxf(a.x * inv + r.x, 0.f);
        h[4 * i + 1] = fmaxf(a.y * inv + r.y, 0.f);
        h[4 * i + 2] = fmaxf(a.z * inv + r.z, 0.f);
        h[4 * i + 3] = fmaxf(a.w * inv + r.w, 0.f);
    }
    float orel[C_OUT], oroot[C_OUT];
    #pragma unroll
    for (int j = 0; j < C_OUT; ++j) { orel[j] = 0.f; oroot[j] = 0.f; }
    #pragma unroll
    for (int k = 0; k < H_MID; ++k) {
        float hk = h[k];
        #pragma unroll
        for (int j = 0; j < C_OUT; ++j) {
            orel[j]  += hk * Wrel2[k * C_OUT + j];
            oroot[j] += hk * Wroot2[k * C_OUT + j];
        }
    }
    #pragma unroll
    for (int j = 0; j < C_OUT; ++j) {
        h2rel[(size_t)n * C_OUT + j]  = orel[j];
        h2root[(size_t)n * C_OUT + j] = oroot[j] + b2[j];
    }
}

// ---------------- K6: scatter layer-2 messages (8 lanes per edge, 5 used) ---
__global__ __launch_bounds__(256) void k6_scatter2(
    const int* __restrict__ src,
    const int* __restrict__ dst,
    const float* __restrict__ h2rel,
    float* __restrict__ agg2) {
    int t = blockIdx.x * 256 + threadIdx.x;
    int e = t >> 3;
    int lane = t & 7;
    if (lane < C_OUT) {
        int s = src[e];
        int d = dst[e];
        atomicAdd(&agg2[(size_t)d * C_OUT + lane],
                  h2rel[(size_t)s * C_OUT + lane]);
    }
}

// ---------------- K7: out = log_softmax(agg2/cnt + h2root) ------------------
__global__ __launch_bounds__(256) void k7_out(
    const float* __restrict__ agg2,
    const float* __restrict__ cnt,
    const float* __restrict__ h2root,
    float* __restrict__ out) {
    int n = blockIdx.x * 256 + threadIdx.x;
    if (n >= N_NODES) return;
    float inv = 1.0f / fmaxf(cnt[n], 1.0f);
    float o[C_OUT];
    #pragma unroll
    for (int j = 0; j < C_OUT; ++j)
        o[j] = agg2[(size_t)n * C_OUT + j] * inv + h2root[(size_t)n * C_OUT + j];
    float m = o[0];
    #pragma unroll
    for (int j = 1; j < C_OUT; ++j) m = fmaxf(m, o[j]);
    float ssum = 0.f;
    #pragma unroll
    for (int j = 0; j < C_OUT; ++j) ssum += expf(o[j] - m);
    float lse = m + logf(ssum);
    #pragma unroll
    for (int j = 0; j < C_OUT; ++j)
        out[(size_t)n * C_OUT + j] = o[j] - lse;
}

extern "C" void kernel_launch(void* const* d_in, const int* in_sizes, int n_in,
                              void* d_out, int out_size, void* d_ws, size_t ws_size,
                              hipStream_t stream) {
    const float* x      = (const float*)d_in[0];
    const int*   ei     = (const int*)d_in[1];   // [2, E] int32
    const float* ew     = (const float*)d_in[2];
    const float* Wrel1  = (const float*)d_in[3];
    const float* Wroot1 = (const float*)d_in[4];
    const float* b1     = (const float*)d_in[5];
    const float* Wrel2  = (const float*)d_in[6];
    const float* Wroot2 = (const float*)d_in[7];
    const float* b2     = (const float*)d_in[8];
    float* out = (float*)d_out;

    const int* src = ei;
    const int* dst = ei + E_EDGES;

    // Workspace layout (floats):
    // [agg1: 32N | cnt: N | agg2: 5N | xrel: 32N | xroot: 32N | h2rel: 5N | h2root: 5N]
    float* ws     = (float*)d_ws;
    float* agg1   = ws;                                // 32N
    float* cnt    = agg1   + (size_t)N_NODES * H_MID;  // N
    float* agg2   = cnt    + N_NODES;                  // 5N
    float* xrel   = agg2   + (size_t)N_NODES * C_OUT;  // 32N
    float* xroot  = xrel   + (size_t)N_NODES * H_MID;  // 32N
    float* h2rel  = xroot  + (size_t)N_NODES * H_MID;  // 5N
    float* h2root = h2rel  + (size_t)N_NODES * C_OUT;  // 5N

    // Zero agg1|cnt|agg2 : 38*N floats contiguous
    int n4 = (N_NODES * 38) / 4;  // 950000 float4s
    k_zero<<<(n4 + 255) / 256, 256, 0, stream>>>((float4*)ws, n4);

    // K1: dense projections
    k1_proj<<<N_NODES / 16, 256, 0, stream>>>(x, Wrel1, Wroot1, b1, xrel, xroot);

    // K3: layer-1 scatter (32 lanes per edge)
    k3_scatter1<<<(E_EDGES * 32) / 256, 256, 0, stream>>>(src, dst, ew, xrel, agg1, cnt);

    // K4: node update + layer-2 projections
    k4_node<<<(N_NODES + 255) / 256, 256, 0, stream>>>(agg1, cnt, xroot,
                                                       Wrel2, Wroot2, b2, h2rel, h2root);

    // K6: layer-2 scatter (8 lanes per edge, 5 active)
    k6_scatter2<<<(E_EDGES * 8) / 256, 256, 0, stream>>>(src, dst, h2rel, agg2);

    // K7: mean + root + log_softmax
    k7_out<<<(N_NODES + 255) / 256, 256, 0, stream>>>(agg2, cnt, h2root, out);
}

// Round 3
// 538.834 us; speedup vs baseline: 1.0898x; 1.0898x over previous
//
#include <hip/hip_runtime.h>
#include <math.h>

#define N_NODES 100000
#define E_EDGES 1600000
#define D_IN    128
#define H_MID   32
#define C_OUT   5
#define NB_SCAN 391   // ceil(N/256)

// ---------------- K1: xrel = x @ W_rel1 ; xroot = x @ W_root1 + b1 ----------
__global__ __launch_bounds__(256) void k1_proj(
    const float* __restrict__ x,
    const float* __restrict__ Wrel,
    const float* __restrict__ Wroot,
    const float* __restrict__ b1,
    float* __restrict__ xrel,
    float* __restrict__ xroot) {
    int tid  = threadIdx.x;
    int node = blockIdx.x * 16 + (tid >> 4);
    int o4   = tid & 15;
    bool isRel = (o4 < 8);
    int col  = isRel ? (o4 * 4) : ((o4 - 8) * 4);
    const float*  Wb   = (isRel ? Wrel : Wroot) + col;
    const float4* xrow = (const float4*)(x + (size_t)node * D_IN);

    float4 acc = make_float4(0.f, 0.f, 0.f, 0.f);
    #pragma unroll 8
    for (int k4 = 0; k4 < D_IN / 4; ++k4) {
        float4 xv = xrow[k4];
        const float* w0 = Wb + (k4 * 4) * H_MID;
        float4 wa = *(const float4*)(w0);
        float4 wb = *(const float4*)(w0 + H_MID);
        float4 wc = *(const float4*)(w0 + 2 * H_MID);
        float4 wd = *(const float4*)(w0 + 3 * H_MID);
        acc.x += xv.x * wa.x + xv.y * wb.x + xv.z * wc.x + xv.w * wd.x;
        acc.y += xv.x * wa.y + xv.y * wb.y + xv.z * wc.y + xv.w * wd.y;
        acc.z += xv.x * wa.z + xv.y * wb.z + xv.z * wc.z + xv.w * wd.z;
        acc.w += xv.x * wa.w + xv.y * wb.w + xv.z * wc.w + xv.w * wd.w;
    }
    if (isRel) {
        *(float4*)(xrel + (size_t)node * H_MID + col) = acc;
    } else {
        acc.x += b1[col + 0]; acc.y += b1[col + 1];
        acc.z += b1[col + 2]; acc.w += b1[col + 3];
        *(float4*)(xroot + (size_t)node * H_MID + col) = acc;
    }
}

// ---------------- CSR build ----------------
__global__ __launch_bounds__(256) void k_zero_int(int* __restrict__ p, int n) {
    int i = blockIdx.x * 256 + threadIdx.x;
    if (i < n) p[i] = 0;
}

__global__ __launch_bounds__(256) void k_hist(const int* __restrict__ dst,
                                              int* __restrict__ deg) {
    int e = blockIdx.x * 256 + threadIdx.x;
    atomicAdd(&deg[dst[e]], 1);
}

__global__ __launch_bounds__(256) void k_scan1(const int* __restrict__ deg,
                                               int* __restrict__ blocksum) {
    __shared__ int s[256];
    int i = blockIdx.x * 256 + threadIdx.x;
    s[threadIdx.x] = (i < N_NODES) ? deg[i] : 0;
    __syncthreads();
    for (int off = 128; off > 0; off >>= 1) {
        if (threadIdx.x < off) s[threadIdx.x] += s[threadIdx.x + off];
        __syncthreads();
    }
    if (threadIdx.x == 0) blocksum[blockIdx.x] = s[0];
}

__global__ void k_scan2(const int* __restrict__ blocksum,
                        int* __restrict__ blockoff) {
    if (threadIdx.x == 0 && blockIdx.x == 0) {
        int run = 0;
        for (int b = 0; b < NB_SCAN; ++b) { blockoff[b] = run; run += blocksum[b]; }
    }
}

__global__ __launch_bounds__(256) void k_scan3(const int* __restrict__ deg,
                                               const int* __restrict__ blockoff,
                                               int* __restrict__ offsets,
                                               int* __restrict__ cursor) {
    __shared__ int s[256];
    int i = blockIdx.x * 256 + threadIdx.x;
    int v = (i < N_NODES) ? deg[i] : 0;
    s[threadIdx.x] = v;
    __syncthreads();
    // Hillis-Steele inclusive scan
    for (int off = 1; off < 256; off <<= 1) {
        int t = (threadIdx.x >= off) ? s[threadIdx.x - off] : 0;
        __syncthreads();
        s[threadIdx.x] += t;
        __syncthreads();
    }
    if (i < N_NODES) {
        int excl = blockoff[blockIdx.x] + s[threadIdx.x] - v;
        offsets[i] = excl;
        cursor[i]  = excl;
    }
}

__global__ __launch_bounds__(256) void k_bucket(const int* __restrict__ src,
                                                const int* __restrict__ dst,
                                                const float* __restrict__ ew,
                                                int* __restrict__ cursor,
                                                int* __restrict__ csr_src,
                                                float* __restrict__ csr_w) {
    int e = blockIdx.x * 256 + threadIdx.x;
    int d = dst[e];
    int pos = atomicAdd(&cursor[d], 1);
    csr_src[pos] = src[e];
    csr_w[pos]   = ew[e];
}

// -------- Layer 1 fused: gather-mean + root + relu + project to 5+5 --------
// 8 nodes per block, 32 lanes per node.
__global__ __launch_bounds__(256) void k_layer1(
    const int* __restrict__ offsets,
    const int* __restrict__ deg,
    const int* __restrict__ csr_src,
    const float* __restrict__ csr_w,
    const float* __restrict__ xrel,
    const float* __restrict__ xroot,
    const float* __restrict__ Wrel2,
    const float* __restrict__ Wroot2,
    const float* __restrict__ b2,
    float* __restrict__ h2rel,
    float* __restrict__ h2root) {
    int node = blockIdx.x * 8 + (threadIdx.x >> 5);
    int lane = threadIdx.x & 31;
    int beg = offsets[node];
    int dg  = deg[node];
    int end = beg + dg;

    float acc = 0.f;
    for (int i = beg; i < end; ++i) {
        int s = csr_src[i];
        float w = csr_w[i];
        acc += xrel[(size_t)s * H_MID + lane] * w;
    }
    float inv = 1.0f / fmaxf((float)dg, 1.0f);
    float h = fmaxf(acc * inv + xroot[(size_t)node * H_MID + lane], 0.f);

    // per-lane partials for 5 rel + 5 root outputs
    float p[2 * C_OUT];
    #pragma unroll
    for (int j = 0; j < C_OUT; ++j) {
        p[j]         = h * Wrel2[lane * C_OUT + j];
        p[C_OUT + j] = h * Wroot2[lane * C_OUT + j];
    }
    // butterfly reduce across the 32 lanes of this node
    #pragma unroll
    for (int m = 16; m > 0; m >>= 1) {
        #pragma unroll
        for (int j = 0; j < 2 * C_OUT; ++j)
            p[j] += __shfl_xor(p[j], m, 32);
    }
    if (lane == 0) {
        #pragma unroll
        for (int j = 0; j < C_OUT; ++j) {
            h2rel[(size_t)node * C_OUT + j]  = p[j];
            h2root[(size_t)node * C_OUT + j] = p[C_OUT + j] + b2[j];
        }
    }
}

// -------- Layer 2: gather-mean of h2rel + h2root → pre-softmax o -----------
// 32 nodes per block, 8 lanes per node (5 active).
__global__ __launch_bounds__(256) void k_layer2(
    const int* __restrict__ offsets,
    const int* __restrict__ deg,
    const int* __restrict__ csr_src,
    const float* __restrict__ h2rel,
    const float* __restrict__ h2root,
    float* __restrict__ tmp_o) {
    int node = blockIdx.x * 32 + (threadIdx.x >> 3);
    int lane = threadIdx.x & 7;
    if (lane >= C_OUT) return;
    int beg = offsets[node];
    int dg  = deg[node];
    int end = beg + dg;
    float acc = 0.f;
    for (int i = beg; i < end; ++i) {
        int s = csr_src[i];
        acc += h2rel[(size_t)s * C_OUT + lane];
    }
    float inv = 1.0f / fmaxf((float)dg, 1.0f);
    tmp_o[(size_t)node * C_OUT + lane] = acc * inv + h2root[(size_t)node * C_OUT + lane];
}

// ---------------- K7: log_softmax ----------------
__global__ __launch_bounds__(256) void k7_out(
    const float* __restrict__ tmp_o,
    float* __restrict__ out) {
    int n = blockIdx.x * 256 + threadIdx.x;
    if (n >= N_NODES) return;
    float o[C_OUT];
    #pragma unroll
    for (int j = 0; j < C_OUT; ++j) o[j] = tmp_o[(size_t)n * C_OUT + j];
    float m = o[0];
    #pragma unroll
    for (int j = 1; j < C_OUT; ++j) m = fmaxf(m, o[j]);
    float ssum = 0.f;
    #pragma unroll
    for (int j = 0; j < C_OUT; ++j) ssum += expf(o[j] - m);
    float lse = m + logf(ssum);
    #pragma unroll
    for (int j = 0; j < C_OUT; ++j)
        out[(size_t)n * C_OUT + j] = o[j] - lse;
}

extern "C" void kernel_launch(void* const* d_in, const int* in_sizes, int n_in,
                              void* d_out, int out_size, void* d_ws, size_t ws_size,
                              hipStream_t stream) {
    const float* x      = (const float*)d_in[0];
    const int*   ei     = (const int*)d_in[1];
    const float* ew     = (const float*)d_in[2];
    const float* Wrel1  = (const float*)d_in[3];
    const float* Wroot1 = (const float*)d_in[4];
    const float* b1     = (const float*)d_in[5];
    const float* Wrel2  = (const float*)d_in[6];
    const float* Wroot2 = (const float*)d_in[7];
    const float* b2     = (const float*)d_in[8];
    float* out = (float*)d_out;

    const int* src = ei;
    const int* dst = ei + E_EDGES;

    // Workspace layout (4-byte units). h2rel/h2root have DEDICATED storage
    // (R2 bug: aliasing them onto xrel raced with k_layer1's xrel gathers).
    // tmp_o aliases xroot (safe: k_layer2 never reads xroot).
    char* ws = (char*)d_ws;
    int*   deg      = (int*)ws;                                 // N
    int*   offsets  = deg + N_NODES;                            // N
    int*   cursor   = offsets + N_NODES;                        // N
    int*   blocksum = cursor + N_NODES;                         // 512
    int*   blockoff = blocksum + 512;                           // 512
    int*   csr_src  = blockoff + 512;                           // E
    float* csr_w    = (float*)(csr_src + E_EDGES);              // E
    float* xrel     = csr_w + E_EDGES;                          // 32N
    float* xroot    = xrel + (size_t)N_NODES * H_MID;           // 32N
    float* h2rel    = xroot + (size_t)N_NODES * H_MID;          // 5N
    float* h2root   = h2rel + (size_t)N_NODES * C_OUT;          // 5N
    float* tmp_o    = xroot;                                    // 5N (alias, safe)

    // --- CSR build ---
    k_zero_int<<<NB_SCAN, 256, 0, stream>>>(deg, N_NODES);
    k_hist<<<E_EDGES / 256, 256, 0, stream>>>(dst, deg);
    k_scan1<<<NB_SCAN, 256, 0, stream>>>(deg, blocksum);
    k_scan2<<<1, 64, 0, stream>>>(blocksum, blockoff);
    k_scan3<<<NB_SCAN, 256, 0, stream>>>(deg, blockoff, offsets, cursor);
    k_bucket<<<E_EDGES / 256, 256, 0, stream>>>(src, dst, ew, cursor, csr_src, csr_w);

    // --- dense projections ---
    k1_proj<<<N_NODES / 16, 256, 0, stream>>>(x, Wrel1, Wroot1, b1, xrel, xroot);

    // --- layer 1 fused gather + node update + layer-2 projections ---
    k_layer1<<<N_NODES / 8, 256, 0, stream>>>(offsets, deg, csr_src, csr_w,
                                              xrel, xroot, Wrel2, Wroot2, b2,
                                              h2rel, h2root);

    // --- layer 2 gather ---
    k_layer2<<<N_NODES / 32, 256, 0, stream>>>(offsets, deg, csr_src,
                                               h2rel, h2root, tmp_o);

    // --- log_softmax ---
    k7_out<<<NB_SCAN, 256, 0, stream>>>(tmp_o, out);
}

// Round 4
// 410.432 us; speedup vs baseline: 1.4307x; 1.3128x over previous
//
#include <hip/hip_runtime.h>
#include <math.h>

#define N_NODES 100000
#define E_EDGES 1600000
#define D_IN    128
#define H_MID   32
#define C_OUT   5
#define NB_SCAN 391   // ceil(N/256)
#define TN      64    // nodes per k1 block
#define XS_STRIDE 132 // 128 + 4 pad floats -> rows 0,4,8,12 alias only 2-way

// ---------------- K1: xrel = x @ W_rel1 ; xroot = x @ W_root1 + b1 ----------
// 64 nodes/block. x tile in LDS (read once from HBM); each thread computes
// 4 outputs x 4 nodes, reusing each W float4 across 4 nodes.
__global__ __launch_bounds__(256) void k1_proj(
    const float* __restrict__ x,
    const float* __restrict__ Wrel,
    const float* __restrict__ Wroot,
    const float* __restrict__ b1,
    float* __restrict__ xrel,
    float* __restrict__ xroot) {
    __shared__ float xs[TN * XS_STRIDE];
    int tid = threadIdx.x;
    int nodeBase = blockIdx.x * TN;

    // Stage 64 rows x 32 float4. 256 threads: 8 rows per pass, 32 f4 per row.
    {
        int r0 = tid >> 5;        // 0..7
        int k4 = tid & 31;        // 0..31
        #pragma unroll
        for (int pass = 0; pass < 8; ++pass) {
            int row = pass * 8 + r0;
            int node = nodeBase + row;
            if (node < N_NODES) {
                float4 v = *(const float4*)(x + (size_t)node * D_IN + k4 * 4);
                *(float4*)(xs + row * XS_STRIDE + k4 * 4) = v;
            }
        }
    }
    __syncthreads();

    int o4 = tid & 15;            // 0..7 rel cols, 8..15 root cols
    int ng = tid >> 4;            // node group 0..15 (4 nodes)
    bool isRel = (o4 < 8);
    int col = (isRel ? o4 : o4 - 8) * 4;
    const float* Wb = (isRel ? Wrel : Wroot) + col;

    const float4* xr0 = (const float4*)(xs + (ng * 4 + 0) * XS_STRIDE);
    const float4* xr1 = (const float4*)(xs + (ng * 4 + 1) * XS_STRIDE);
    const float4* xr2 = (const float4*)(xs + (ng * 4 + 2) * XS_STRIDE);
    const float4* xr3 = (const float4*)(xs + (ng * 4 + 3) * XS_STRIDE);

    float4 acc[4];
    #pragma unroll
    for (int n = 0; n < 4; ++n) acc[n] = make_float4(0.f, 0.f, 0.f, 0.f);

    #pragma unroll 4
    for (int k4 = 0; k4 < D_IN / 4; ++k4) {
        const float* w0 = Wb + (k4 * 4) * H_MID;
        float4 wa = *(const float4*)(w0);
        float4 wb = *(const float4*)(w0 + H_MID);
        float4 wc = *(const float4*)(w0 + 2 * H_MID);
        float4 wd = *(const float4*)(w0 + 3 * H_MID);
        float4 xv0 = xr0[k4], xv1 = xr1[k4], xv2 = xr2[k4], xv3 = xr3[k4];
        #pragma unroll
        for (int n = 0; n < 4; ++n) {
            float4 xv = (n == 0) ? xv0 : (n == 1) ? xv1 : (n == 2) ? xv2 : xv3;
            acc[n].x += xv.x * wa.x + xv.y * wb.x + xv.z * wc.x + xv.w * wd.x;
            acc[n].y += xv.x * wa.y + xv.y * wb.y + xv.z * wc.y + xv.w * wd.y;
            acc[n].z += xv.x * wa.z + xv.y * wb.z + xv.z * wc.z + xv.w * wd.z;
            acc[n].w += xv.x * wa.w + xv.y * wb.w + xv.z * wc.w + xv.w * wd.w;
        }
    }

    float4 bv = make_float4(0.f, 0.f, 0.f, 0.f);
    if (!isRel) {
        bv.x = b1[col]; bv.y = b1[col + 1]; bv.z = b1[col + 2]; bv.w = b1[col + 3];
    }
    #pragma unroll
    for (int n = 0; n < 4; ++n) {
        int node = nodeBase + ng * 4 + n;
        if (node < N_NODES) {
            float4 v = make_float4(acc[n].x + bv.x, acc[n].y + bv.y,
                                   acc[n].z + bv.z, acc[n].w + bv.w);
            float* dstp = (isRel ? xrel : xroot) + (size_t)node * H_MID + col;
            *(float4*)dstp = v;
        }
    }
}

// ---------------- CSR build ----------------
__global__ __launch_bounds__(256) void k_zero_int(int* __restrict__ p, int n) {
    int i = blockIdx.x * 256 + threadIdx.x;
    if (i < n) p[i] = 0;
}

__global__ __launch_bounds__(256) void k_hist(const int* __restrict__ dst,
                                              int* __restrict__ deg) {
    int e = blockIdx.x * 256 + threadIdx.x;
    atomicAdd(&deg[dst[e]], 1);
}

__global__ __launch_bounds__(256) void k_scan1(const int* __restrict__ deg,
                                               int* __restrict__ blocksum) {
    __shared__ int s[256];
    int i = blockIdx.x * 256 + threadIdx.x;
    s[threadIdx.x] = (i < N_NODES) ? deg[i] : 0;
    __syncthreads();
    for (int off = 128; off > 0; off >>= 1) {
        if (threadIdx.x < off) s[threadIdx.x] += s[threadIdx.x + off];
        __syncthreads();
    }
    if (threadIdx.x == 0) blocksum[blockIdx.x] = s[0];
}

// single-block 512-thread Hillis-Steele scan over NB_SCAN block sums
__global__ __launch_bounds__(512) void k_scan2(const int* __restrict__ blocksum,
                                               int* __restrict__ blockoff) {
    __shared__ int s[512];
    int i = threadIdx.x;
    int v = (i < NB_SCAN) ? blocksum[i] : 0;
    s[i] = v;
    __syncthreads();
    for (int off = 1; off < 512; off <<= 1) {
        int t = (i >= off) ? s[i - off] : 0;
        __syncthreads();
        s[i] += t;
        __syncthreads();
    }
    if (i < NB_SCAN) blockoff[i] = s[i] - v;   // exclusive
}

__global__ __launch_bounds__(256) void k_scan3(const int* __restrict__ deg,
                                               const int* __restrict__ blockoff,
                                               int* __restrict__ offsets,
                                               int* __restrict__ cursor) {
    __shared__ int s[256];
    int i = blockIdx.x * 256 + threadIdx.x;
    int v = (i < N_NODES) ? deg[i] : 0;
    s[threadIdx.x] = v;
    __syncthreads();
    for (int off = 1; off < 256; off <<= 1) {
        int t = (threadIdx.x >= off) ? s[threadIdx.x - off] : 0;
        __syncthreads();
        s[threadIdx.x] += t;
        __syncthreads();
    }
    if (i < N_NODES) {
        int excl = blockoff[blockIdx.x] + s[threadIdx.x] - v;
        offsets[i] = excl;
        cursor[i]  = excl;
    }
}

__global__ __launch_bounds__(256) void k_bucket(const int* __restrict__ src,
                                                const int* __restrict__ dst,
                                                const float* __restrict__ ew,
                                                int* __restrict__ cursor,
                                                int* __restrict__ csr_src,
                                                float* __restrict__ csr_w) {
    int e = blockIdx.x * 256 + threadIdx.x;
    int d = dst[e];
    int pos = atomicAdd(&cursor[d], 1);
    csr_src[pos] = src[e];
    csr_w[pos]   = ew[e];
}

// -------- Layer 1 fused: gather-mean + root + relu + project to 5+5 --------
// 8 nodes per block, 32 lanes per node. Gather loop unrolled x4 so 4 row
// fetches are in flight per iteration.
__global__ __launch_bounds__(256) void k_layer1(
    const int* __restrict__ offsets,
    const int* __restrict__ deg,
    const int* __restrict__ csr_src,
    const float* __restrict__ csr_w,
    const float* __restrict__ xrel,
    const float* __restrict__ xroot,
    const float* __restrict__ Wrel2,
    const float* __restrict__ Wroot2,
    const float* __restrict__ b2,
    float* __restrict__ h2rel,
    float* __restrict__ h2root) {
    int node = blockIdx.x * 8 + (threadIdx.x >> 5);
    int lane = threadIdx.x & 31;
    int beg = offsets[node];
    int dg  = deg[node];
    int end = beg + dg;

    float acc = 0.f;
    int i = beg;
    for (; i + 4 <= end; i += 4) {
        int s0 = csr_src[i];
        int s1 = csr_src[i + 1];
        int s2 = csr_src[i + 2];
        int s3 = csr_src[i + 3];
        float w0 = csr_w[i];
        float w1 = csr_w[i + 1];
        float w2 = csr_w[i + 2];
        float w3 = csr_w[i + 3];
        float v0 = xrel[(size_t)s0 * H_MID + lane];
        float v1 = xrel[(size_t)s1 * H_MID + lane];
        float v2 = xrel[(size_t)s2 * H_MID + lane];
        float v3 = xrel[(size_t)s3 * H_MID + lane];
        acc += v0 * w0 + v1 * w1 + v2 * w2 + v3 * w3;
    }
    for (; i < end; ++i)
        acc += xrel[(size_t)csr_src[i] * H_MID + lane] * csr_w[i];

    float inv = 1.0f / fmaxf((float)dg, 1.0f);
    float h = fmaxf(acc * inv + xroot[(size_t)node * H_MID + lane], 0.f);

    float p[2 * C_OUT];
    #pragma unroll
    for (int j = 0; j < C_OUT; ++j) {
        p[j]         = h * Wrel2[lane * C_OUT + j];
        p[C_OUT + j] = h * Wroot2[lane * C_OUT + j];
    }
    #pragma unroll
    for (int m = 16; m > 0; m >>= 1) {
        #pragma unroll
        for (int j = 0; j < 2 * C_OUT; ++j)
            p[j] += __shfl_xor(p[j], m, 32);
    }
    if (lane == 0) {
        #pragma unroll
        for (int j = 0; j < C_OUT; ++j) {
            h2rel[(size_t)node * C_OUT + j]  = p[j];
            h2root[(size_t)node * C_OUT + j] = p[C_OUT + j] + b2[j];
        }
    }
}

// -------- Layer 2 + log_softmax fused: 32 nodes/block, 8 lanes/node --------
__global__ __launch_bounds__(256) void k_layer2(
    const int* __restrict__ offsets,
    const int* __restrict__ deg,
    const int* __restrict__ csr_src,
    const float* __restrict__ h2rel,
    const float* __restrict__ h2root,
    float* __restrict__ out) {
    int node = blockIdx.x * 32 + (threadIdx.x >> 3);
    int lane = threadIdx.x & 7;
    int beg = offsets[node];
    int dg  = deg[node];
    int end = beg + dg;

    float acc = 0.f;
    if (lane < C_OUT) {
        int i = beg;
        for (; i + 4 <= end; i += 4) {
            int s0 = csr_src[i];
            int s1 = csr_src[i + 1];
            int s2 = csr_src[i + 2];
            int s3 = csr_src[i + 3];
            float v0 = h2rel[(size_t)s0 * C_OUT + lane];
            float v1 = h2rel[(size_t)s1 * C_OUT + lane];
            float v2 = h2rel[(size_t)s2 * C_OUT + lane];
            float v3 = h2rel[(size_t)s3 * C_OUT + lane];
            acc += v0 + v1 + v2 + v3;
        }
        for (; i < end; ++i)
            acc += h2rel[(size_t)csr_src[i] * C_OUT + lane];
    }
    float inv = 1.0f / fmaxf((float)dg, 1.0f);
    float o = (lane < C_OUT)
                  ? acc * inv + h2root[(size_t)node * C_OUT + lane]
                  : -INFINITY;
    // max over the 8-lane group
    float m = o;
    #pragma unroll
    for (int d = 4; d > 0; d >>= 1) m = fmaxf(m, __shfl_xor(m, d, 8));
    float e = (lane < C_OUT) ? expf(o - m) : 0.f;
    float ssum = e;
    #pragma unroll
    for (int d = 4; d > 0; d >>= 1) ssum += __shfl_xor(ssum, d, 8);
    float lse = m + logf(ssum);
    if (lane < C_OUT)
        out[(size_t)node * C_OUT + lane] = o - lse;
}

extern "C" void kernel_launch(void* const* d_in, const int* in_sizes, int n_in,
                              void* d_out, int out_size, void* d_ws, size_t ws_size,
                              hipStream_t stream) {
    const float* x      = (const float*)d_in[0];
    const int*   ei     = (const int*)d_in[1];
    const float* ew     = (const float*)d_in[2];
    const float* Wrel1  = (const float*)d_in[3];
    const float* Wroot1 = (const float*)d_in[4];
    const float* b1     = (const float*)d_in[5];
    const float* Wrel2  = (const float*)d_in[6];
    const float* Wroot2 = (const float*)d_in[7];
    const float* b2     = (const float*)d_in[8];
    float* out = (float*)d_out;

    const int* src = ei;
    const int* dst = ei + E_EDGES;

    // Workspace layout. h2rel/h2root dedicated (R2 aliasing bug).
    char* ws = (char*)d_ws;
    int*   deg      = (int*)ws;                                 // N
    int*   offsets  = deg + N_NODES;                            // N
    int*   cursor   = offsets + N_NODES;                        // N
    int*   blocksum = cursor + N_NODES;                         // 512
    int*   blockoff = blocksum + 512;                           // 512
    int*   csr_src  = blockoff + 512;                           // E
    float* csr_w    = (float*)(csr_src + E_EDGES);              // E
    float* xrel     = csr_w + E_EDGES;                          // 32N
    float* xroot    = xrel + (size_t)N_NODES * H_MID;           // 32N
    float* h2rel    = xroot + (size_t)N_NODES * H_MID;          // 5N
    float* h2root   = h2rel + (size_t)N_NODES * C_OUT;          // 5N

    // --- CSR build ---
    k_zero_int<<<NB_SCAN, 256, 0, stream>>>(deg, N_NODES);
    k_hist<<<E_EDGES / 256, 256, 0, stream>>>(dst, deg);
    k_scan1<<<NB_SCAN, 256, 0, stream>>>(deg, blocksum);
    k_scan2<<<1, 512, 0, stream>>>(blocksum, blockoff);
    k_scan3<<<NB_SCAN, 256, 0, stream>>>(deg, blockoff, offsets, cursor);
    k_bucket<<<E_EDGES / 256, 256, 0, stream>>>(src, dst, ew, cursor, csr_src, csr_w);

    // --- dense projections ---
    k1_proj<<<(N_NODES + TN - 1) / TN, 256, 0, stream>>>(x, Wrel1, Wroot1, b1,
                                                         xrel, xroot);

    // --- layer 1 fused gather + node update + layer-2 projections ---
    k_layer1<<<N_NODES / 8, 256, 0, stream>>>(offsets, deg, csr_src, csr_w,
                                              xrel, xroot, Wrel2, Wroot2, b2,
                                              h2rel, h2root);

    // --- layer 2 gather + log_softmax (fused) ---
    k_layer2<<<N_NODES / 32, 256, 0, stream>>>(offsets, deg, csr_src,
                                               h2rel, h2root, out);
}

// Round 5
// 382.133 us; speedup vs baseline: 1.5367x; 1.0741x over previous
//
#include <hip/hip_runtime.h>
#include <math.h>

#define N_NODES 100000
#define E_EDGES 1600000
#define D_IN    128
#define H_MID   32
#define C_OUT   5
#define NB_SCAN 391   // ceil(N/256)
#define TN      64    // nodes per k1 block
#define XS_STRIDE 132 // 128 + 4 pad floats

#define NBKT   98     // coarse buckets: dst>>10, 99999>>10 = 97
#define BSHIFT 10
#define BCAP   17500  // per-bucket staging capacity (avg 16327, +5 sigma ~ 17000)

// ---------------- K1: xrel = x @ W_rel1 ; xroot = x @ W_root1 + b1 ----------
__global__ __launch_bounds__(256) void k1_proj(
    const float* __restrict__ x,
    const float* __restrict__ Wrel,
    const float* __restrict__ Wroot,
    const float* __restrict__ b1,
    float* __restrict__ xrel,
    float* __restrict__ xroot) {
    __shared__ float xs[TN * XS_STRIDE];
    int tid = threadIdx.x;
    int nodeBase = blockIdx.x * TN;

    {
        int r0 = tid >> 5;
        int k4 = tid & 31;
        #pragma unroll
        for (int pass = 0; pass < 8; ++pass) {
            int row = pass * 8 + r0;
            int node = nodeBase + row;
            if (node < N_NODES) {
                float4 v = *(const float4*)(x + (size_t)node * D_IN + k4 * 4);
                *(float4*)(xs + row * XS_STRIDE + k4 * 4) = v;
            }
        }
    }
    __syncthreads();

    int o4 = tid & 15;
    int ng = tid >> 4;
    bool isRel = (o4 < 8);
    int col = (isRel ? o4 : o4 - 8) * 4;
    const float* Wb = (isRel ? Wrel : Wroot) + col;

    const float4* xr0 = (const float4*)(xs + (ng * 4 + 0) * XS_STRIDE);
    const float4* xr1 = (const float4*)(xs + (ng * 4 + 1) * XS_STRIDE);
    const float4* xr2 = (const float4*)(xs + (ng * 4 + 2) * XS_STRIDE);
    const float4* xr3 = (const float4*)(xs + (ng * 4 + 3) * XS_STRIDE);

    float4 acc[4];
    #pragma unroll
    for (int n = 0; n < 4; ++n) acc[n] = make_float4(0.f, 0.f, 0.f, 0.f);

    #pragma unroll 4
    for (int k4 = 0; k4 < D_IN / 4; ++k4) {
        const float* w0 = Wb + (k4 * 4) * H_MID;
        float4 wa = *(const float4*)(w0);
        float4 wb = *(const float4*)(w0 + H_MID);
        float4 wc = *(const float4*)(w0 + 2 * H_MID);
        float4 wd = *(const float4*)(w0 + 3 * H_MID);
        float4 xv0 = xr0[k4], xv1 = xr1[k4], xv2 = xr2[k4], xv3 = xr3[k4];
        #pragma unroll
        for (int n = 0; n < 4; ++n) {
            float4 xv = (n == 0) ? xv0 : (n == 1) ? xv1 : (n == 2) ? xv2 : xv3;
            acc[n].x += xv.x * wa.x + xv.y * wb.x + xv.z * wc.x + xv.w * wd.x;
            acc[n].y += xv.x * wa.y + xv.y * wb.y + xv.z * wc.y + xv.w * wd.y;
            acc[n].z += xv.x * wa.z + xv.y * wb.z + xv.z * wc.z + xv.w * wd.z;
            acc[n].w += xv.x * wa.w + xv.y * wb.w + xv.z * wc.w + xv.w * wd.w;
        }
    }

    float4 bv = make_float4(0.f, 0.f, 0.f, 0.f);
    if (!isRel) {
        bv.x = b1[col]; bv.y = b1[col + 1]; bv.z = b1[col + 2]; bv.w = b1[col + 3];
    }
    #pragma unroll
    for (int n = 0; n < 4; ++n) {
        int node = nodeBase + ng * 4 + n;
        if (node < N_NODES) {
            float4 v = make_float4(acc[n].x + bv.x, acc[n].y + bv.y,
                                   acc[n].z + bv.z, acc[n].w + bv.w);
            float* dstp = (isRel ? xrel : xroot) + (size_t)node * H_MID + col;
            *(float4*)dstp = v;
        }
    }
}

// ---------------- CSR build: degree + offsets ----------------
__global__ __launch_bounds__(256) void k_zero_int(int* __restrict__ p, int n) {
    int i = blockIdx.x * 256 + threadIdx.x;
    if (i < n) p[i] = 0;
}

__global__ __launch_bounds__(256) void k_hist(const int* __restrict__ dst,
                                              int* __restrict__ deg) {
    int e = blockIdx.x * 256 + threadIdx.x;
    atomicAdd(&deg[dst[e]], 1);
}

__global__ __launch_bounds__(256) void k_scan1(const int* __restrict__ deg,
                                               int* __restrict__ blocksum) {
    __shared__ int s[256];
    int i = blockIdx.x * 256 + threadIdx.x;
    s[threadIdx.x] = (i < N_NODES) ? deg[i] : 0;
    __syncthreads();
    for (int off = 128; off > 0; off >>= 1) {
        if (threadIdx.x < off) s[threadIdx.x] += s[threadIdx.x + off];
        __syncthreads();
    }
    if (threadIdx.x == 0) blocksum[blockIdx.x] = s[0];
}

__global__ __launch_bounds__(512) void k_scan2(const int* __restrict__ blocksum,
                                               int* __restrict__ blockoff) {
    __shared__ int s[512];
    int i = threadIdx.x;
    int v = (i < NB_SCAN) ? blocksum[i] : 0;
    s[i] = v;
    __syncthreads();
    for (int off = 1; off < 512; off <<= 1) {
        int t = (i >= off) ? s[i - off] : 0;
        __syncthreads();
        s[i] += t;
        __syncthreads();
    }
    if (i < NB_SCAN) blockoff[i] = s[i] - v;
}

__global__ __launch_bounds__(256) void k_scan3(const int* __restrict__ deg,
                                               const int* __restrict__ blockoff,
                                               int* __restrict__ offsets,
                                               int* __restrict__ cursorF) {
    __shared__ int s[256];
    int i = blockIdx.x * 256 + threadIdx.x;
    int v = (i < N_NODES) ? deg[i] : 0;
    s[threadIdx.x] = v;
    __syncthreads();
    for (int off = 1; off < 256; off <<= 1) {
        int t = (threadIdx.x >= off) ? s[threadIdx.x - off] : 0;
        __syncthreads();
        s[threadIdx.x] += t;
        __syncthreads();
    }
    if (i < N_NODES) {
        int excl = blockoff[blockIdx.x] + s[threadIdx.x] - v;
        offsets[i] = excl;
        cursorF[i] = excl;
    }
}

// -------- Pass A: counting-sort 1024 edges by coarse bucket in LDS, --------
// -------- write contiguous per-bucket runs into staged area        --------
__global__ __launch_bounds__(1024) void k_binA(
    const int* __restrict__ src,
    const int* __restrict__ dst,
    const float* __restrict__ ew,
    int* __restrict__ bucket_cursor,
    int* __restrict__ staged) {
    __shared__ int cnt[NBKT];
    __shared__ int lstart[NBKT];
    __shared__ int gbase[NBKT];
    __shared__ int scanbuf[128];
    __shared__ int ebuf[1024 * 3];
    int tid = threadIdx.x;
    int e = blockIdx.x * 1024 + tid;

    if (tid < NBKT) cnt[tid] = 0;
    __syncthreads();

    int d = 0, s = 0, b = 0, rank = 0, wbits = 0;
    bool valid = (e < E_EDGES);
    if (valid) {
        d = dst[e]; s = src[e]; wbits = __float_as_int(ew[e]);
        b = d >> BSHIFT;
        rank = atomicAdd(&cnt[b], 1);
    }
    __syncthreads();

    // inclusive scan of cnt over 128 slots (98 live)
    if (tid < 128) scanbuf[tid] = (tid < NBKT) ? cnt[tid] : 0;
    __syncthreads();
    for (int off = 1; off < 128; off <<= 1) {
        int t = 0;
        if (tid < 128 && tid >= off) t = scanbuf[tid - off];
        __syncthreads();
        if (tid < 128) scanbuf[tid] += t;
        __syncthreads();
    }
    if (tid < NBKT) {
        lstart[tid] = scanbuf[tid] - cnt[tid];               // exclusive
        gbase[tid]  = atomicAdd(&bucket_cursor[tid], cnt[tid]);
    }
    __syncthreads();
    int total = scanbuf[NBKT - 1];

    if (valid) {
        int slot = lstart[b] + rank;
        ebuf[slot * 3 + 0] = d;
        ebuf[slot * 3 + 1] = s;
        ebuf[slot * 3 + 2] = wbits;
    }
    __syncthreads();

    if (tid < total) {
        int dd = ebuf[tid * 3 + 0];
        int bb = dd >> BSHIFT;
        int gpos = gbase[bb] + (tid - lstart[bb]);   // index within bucket region
        if (gpos < BCAP) {
            int* outp = staged + ((size_t)bb * BCAP + gpos) * 3;
            outp[0] = dd;
            outp[1] = ebuf[tid * 3 + 1];
            outp[2] = ebuf[tid * 3 + 2];
        }
    }
}

// -------- Pass B: one block per bucket; fine scatter into L2-local region --
__global__ __launch_bounds__(1024) void k_binB(
    const int* __restrict__ bucket_cursor,
    const int* __restrict__ staged,
    int* __restrict__ cursorF,
    int2* __restrict__ csr8) {
    int b = blockIdx.x;
    int count = bucket_cursor[b];
    if (count > BCAP) count = BCAP;
    const int* sp = staged + (size_t)b * BCAP * 3;
    for (int i = threadIdx.x; i < count; i += 1024) {
        int d = sp[i * 3 + 0];
        int s = sp[i * 3 + 1];
        int w = sp[i * 3 + 2];
        int pos = atomicAdd(&cursorF[d], 1);
        csr8[pos] = make_int2(s, w);
    }
}

// -------- Layer 1 fused: gather-mean + root + relu + project to 5+5 --------
__global__ __launch_bounds__(256) void k_layer1(
    const int* __restrict__ offsets,
    const int* __restrict__ deg,
    const int2* __restrict__ csr8,
    const float* __restrict__ xrel,
    const float* __restrict__ xroot,
    const float* __restrict__ Wrel2,
    const float* __restrict__ Wroot2,
    const float* __restrict__ b2,
    float* __restrict__ h2rel,
    float* __restrict__ h2root) {
    int node = blockIdx.x * 8 + (threadIdx.x >> 5);
    int lane = threadIdx.x & 31;
    int beg = offsets[node];
    int dg  = deg[node];
    int end = beg + dg;

    float acc = 0.f;
    int i = beg;
    for (; i + 4 <= end; i += 4) {
        int2 e0 = csr8[i];
        int2 e1 = csr8[i + 1];
        int2 e2 = csr8[i + 2];
        int2 e3 = csr8[i + 3];
        float v0 = xrel[(size_t)e0.x * H_MID + lane];
        float v1 = xrel[(size_t)e1.x * H_MID + lane];
        float v2 = xrel[(size_t)e2.x * H_MID + lane];
        float v3 = xrel[(size_t)e3.x * H_MID + lane];
        acc += v0 * __int_as_float(e0.y) + v1 * __int_as_float(e1.y)
             + v2 * __int_as_float(e2.y) + v3 * __int_as_float(e3.y);
    }
    for (; i < end; ++i) {
        int2 e0 = csr8[i];
        acc += xrel[(size_t)e0.x * H_MID + lane] * __int_as_float(e0.y);
    }

    float inv = 1.0f / fmaxf((float)dg, 1.0f);
    float h = fmaxf(acc * inv + xroot[(size_t)node * H_MID + lane], 0.f);

    float p[2 * C_OUT];
    #pragma unroll
    for (int j = 0; j < C_OUT; ++j) {
        p[j]         = h * Wrel2[lane * C_OUT + j];
        p[C_OUT + j] = h * Wroot2[lane * C_OUT + j];
    }
    #pragma unroll
    for (int m = 16; m > 0; m >>= 1) {
        #pragma unroll
        for (int j = 0; j < 2 * C_OUT; ++j)
            p[j] += __shfl_xor(p[j], m, 32);
    }
    if (lane == 0) {
        #pragma unroll
        for (int j = 0; j < C_OUT; ++j) {
            h2rel[(size_t)node * C_OUT + j]  = p[j];
            h2root[(size_t)node * C_OUT + j] = p[C_OUT + j] + b2[j];
        }
    }
}

// -------- Layer 2 + log_softmax fused: 32 nodes/block, 8 lanes/node --------
__global__ __launch_bounds__(256) void k_layer2(
    const int* __restrict__ offsets,
    const int* __restrict__ deg,
    const int2* __restrict__ csr8,
    const float* __restrict__ h2rel,
    const float* __restrict__ h2root,
    float* __restrict__ out) {
    int node = blockIdx.x * 32 + (threadIdx.x >> 3);
    int lane = threadIdx.x & 7;
    int beg = offsets[node];
    int dg  = deg[node];
    int end = beg + dg;

    float acc = 0.f;
    if (lane < C_OUT) {
        int i = beg;
        for (; i + 4 <= end; i += 4) {
            int s0 = csr8[i].x;
            int s1 = csr8[i + 1].x;
            int s2 = csr8[i + 2].x;
            int s3 = csr8[i + 3].x;
            float v0 = h2rel[(size_t)s0 * C_OUT + lane];
            float v1 = h2rel[(size_t)s1 * C_OUT + lane];
            float v2 = h2rel[(size_t)s2 * C_OUT + lane];
            float v3 = h2rel[(size_t)s3 * C_OUT + lane];
            acc += v0 + v1 + v2 + v3;
        }
        for (; i < end; ++i)
            acc += h2rel[(size_t)csr8[i].x * C_OUT + lane];
    }
    float inv = 1.0f / fmaxf((float)dg, 1.0f);
    float o = (lane < C_OUT)
                  ? acc * inv + h2root[(size_t)node * C_OUT + lane]
                  : -INFINITY;
    float m = o;
    #pragma unroll
    for (int dd = 4; dd > 0; dd >>= 1) m = fmaxf(m, __shfl_xor(m, dd, 8));
    float e = (lane < C_OUT) ? expf(o - m) : 0.f;
    float ssum = e;
    #pragma unroll
    for (int dd = 4; dd > 0; dd >>= 1) ssum += __shfl_xor(ssum, dd, 8);
    float lse = m + logf(ssum);
    if (lane < C_OUT)
        out[(size_t)node * C_OUT + lane] = o - lse;
}

extern "C" void kernel_launch(void* const* d_in, const int* in_sizes, int n_in,
                              void* d_out, int out_size, void* d_ws, size_t ws_size,
                              hipStream_t stream) {
    const float* x      = (const float*)d_in[0];
    const int*   ei     = (const int*)d_in[1];
    const float* ew     = (const float*)d_in[2];
    const float* Wrel1  = (const float*)d_in[3];
    const float* Wroot1 = (const float*)d_in[4];
    const float* b1     = (const float*)d_in[5];
    const float* Wrel2  = (const float*)d_in[6];
    const float* Wroot2 = (const float*)d_in[7];
    const float* b2     = (const float*)d_in[8];
    float* out = (float*)d_out;

    const int* src = ei;
    const int* dst = ei + E_EDGES;

    // Workspace layout (ints/floats, 4B units):
    // deg N | bucket_cursor 128 | offsets N | cursorF N | blocksum 512 |
    // blockoff 512 | csr8 2E | xrel 32N | xroot 32N | h2rel 5N | h2root 5N
    // staged (98*17500*3 ints = 20.6MB) aliases xrel+xroot (25.6MB) — dead
    // before k1_proj runs (stream-serial).
    char* ws = (char*)d_ws;
    int*   deg           = (int*)ws;                            // N
    int*   bucket_cursor = deg + N_NODES;                       // 128
    int*   offsets       = bucket_cursor + 128;                 // N
    int*   cursorF       = offsets + N_NODES;                   // N
    int*   blocksum      = cursorF + N_NODES;                   // 512
    int*   blockoff      = blocksum + 512;                      // 512
    int2*  csr8          = (int2*)(blockoff + 512);             // E int2
    float* xrel          = (float*)(csr8 + E_EDGES);            // 32N
    float* xroot         = xrel + (size_t)N_NODES * H_MID;      // 32N
    float* h2rel         = xroot + (size_t)N_NODES * H_MID;     // 5N
    float* h2root        = h2rel + (size_t)N_NODES * C_OUT;     // 5N
    int*   staged        = (int*)xrel;                          // alias (dead by k1_proj)

    // --- degree + offsets ---
    k_zero_int<<<(N_NODES + 128 + 255) / 256, 256, 0, stream>>>(deg, N_NODES + 128);
    k_hist<<<E_EDGES / 256, 256, 0, stream>>>(dst, deg);
    k_scan1<<<NB_SCAN, 256, 0, stream>>>(deg, blocksum);
    k_scan2<<<1, 512, 0, stream>>>(blocksum, blockoff);
    k_scan3<<<NB_SCAN, 256, 0, stream>>>(deg, blockoff, offsets, cursorF);

    // --- two-pass binned CSR build ---
    k_binA<<<(E_EDGES + 1023) / 1024, 1024, 0, stream>>>(src, dst, ew,
                                                         bucket_cursor, staged);
    k_binB<<<NBKT, 1024, 0, stream>>>(bucket_cursor, staged, cursorF, csr8);

    // --- dense projections (after staging is dead) ---
    k1_proj<<<(N_NODES + TN - 1) / TN, 256, 0, stream>>>(x, Wrel1, Wroot1, b1,
                                                         xrel, xroot);

    // --- layer 1 fused gather + node update + layer-2 projections ---
    k_layer1<<<N_NODES / 8, 256, 0, stream>>>(offsets, deg, csr8,
                                              xrel, xroot, Wrel2, Wroot2, b2,
                                              h2rel, h2root);

    // --- layer 2 gather + log_softmax (fused) ---
    k_layer2<<<N_NODES / 32, 256, 0, stream>>>(offsets, deg, csr8,
                                               h2rel, h2root, out);
}

// Round 6
// 365.246 us; speedup vs baseline: 1.6077x; 1.0462x over previous
//
#include <hip/hip_runtime.h>
#include <math.h>

#define N_NODES 100000
#define E_EDGES 1600000
#define D_IN    128
#define H_MID   32
#define C_OUT   5
#define NB_SCAN 391   // ceil(N/256)
#define TN      64    // nodes per k1 block
#define XS_STRIDE 132 // 128 + 4 pad floats

#define NBKT   98     // coarse buckets: dst>>10, 99999>>10 = 97
#define BSHIFT 10
#define BCAP   17500  // per-bucket staging capacity (avg 16327, max ~16850)

// ---------------- K1: xrel = x @ W_rel1 ; xroot = x @ W_root1 + b1 ----------
// 1024 threads = 16 waves; each wave owns one 4-col group (8 rel + 8 root),
// lanes = 64 nodes. W panel is wave-uniform (readfirstlane) -> s_load into
// SGPRs; x tile staged once to LDS. VALU-bound: 512 v_fma per lane.
__global__ __launch_bounds__(1024) void k1_proj(
    const float* __restrict__ x,
    const float* __restrict__ Wrel,
    const float* __restrict__ Wroot,
    const float* __restrict__ b1,
    float* __restrict__ xrel,
    float* __restrict__ xroot) {
    __shared__ float xs[TN * XS_STRIDE];
    int tid = threadIdx.x;
    int nodeBase = blockIdx.x * TN;

    // Stage 64 rows x 32 float4 (2048 f4, 1024 threads -> 2 each, coalesced)
    #pragma unroll
    for (int t = tid; t < TN * 32; t += 1024) {
        int row = t >> 5;
        int k4  = t & 31;
        int node = nodeBase + row;
        float4 v = make_float4(0.f, 0.f, 0.f, 0.f);
        if (node < N_NODES)
            v = *(const float4*)(x + (size_t)node * D_IN + k4 * 4);
        *(float4*)(xs + row * XS_STRIDE + k4 * 4) = v;
    }
    __syncthreads();

    int lane = tid & 63;
    int colgrp = __builtin_amdgcn_readfirstlane(tid >> 6);  // 0..15, wave-uniform
    bool isRel = (colgrp < 8);
    int col = (isRel ? colgrp : colgrp - 8) * 4;
    const float* Wb = (isRel ? Wrel : Wroot) + col;   // uniform base -> s_load
    const float* xr = xs + lane * XS_STRIDE;

    float4 acc = make_float4(0.f, 0.f, 0.f, 0.f);
    #pragma unroll 8
    for (int k4 = 0; k4 < D_IN / 4; ++k4) {
        float4 xv = *(const float4*)(xr + k4 * 4);
        const float* w0 = Wb + (k4 * 4) * H_MID;
        float4 wa = *(const float4*)(w0);
        float4 wb = *(const float4*)(w0 + H_MID);
        float4 wc = *(const float4*)(w0 + 2 * H_MID);
        float4 wd = *(const float4*)(w0 + 3 * H_MID);
        acc.x += xv.x * wa.x + xv.y * wb.x + xv.z * wc.x + xv.w * wd.x;
        acc.y += xv.x * wa.y + xv.y * wb.y + xv.z * wc.y + xv.w * wd.y;
        acc.z += xv.x * wa.z + xv.y * wb.z + xv.z * wc.z + xv.w * wd.z;
        acc.w += xv.x * wa.w + xv.y * wb.w + xv.z * wc.w + xv.w * wd.w;
    }

    int node = nodeBase + lane;
    if (node < N_NODES) {
        if (isRel) {
            *(float4*)(xrel + (size_t)node * H_MID + col) = acc;
        } else {
            acc.x += b1[col + 0]; acc.y += b1[col + 1];
            acc.z += b1[col + 2]; acc.w += b1[col + 3];
            *(float4*)(xroot + (size_t)node * H_MID + col) = acc;
        }
    }
}

// ---------------- CSR build: degree + offsets ----------------
__global__ __launch_bounds__(256) void k_zero_int(int* __restrict__ p, int n) {
    int i = blockIdx.x * 256 + threadIdx.x;
    if (i < n) p[i] = 0;
}

__global__ __launch_bounds__(256) void k_hist(const int* __restrict__ dst,
                                              int* __restrict__ deg) {
    int e = blockIdx.x * 256 + threadIdx.x;
    atomicAdd(&deg[dst[e]], 1);
}

__global__ __launch_bounds__(256) void k_scan1(const int* __restrict__ deg,
                                               int* __restrict__ blocksum) {
    __shared__ int s[256];
    int i = blockIdx.x * 256 + threadIdx.x;
    s[threadIdx.x] = (i < N_NODES) ? deg[i] : 0;
    __syncthreads();
    for (int off = 128; off > 0; off >>= 1) {
        if (threadIdx.x < off) s[threadIdx.x] += s[threadIdx.x + off];
        __syncthreads();
    }
    if (threadIdx.x == 0) blocksum[blockIdx.x] = s[0];
}

__global__ __launch_bounds__(512) void k_scan2(const int* __restrict__ blocksum,
                                               int* __restrict__ blockoff) {
    __shared__ int s[512];
    int i = threadIdx.x;
    int v = (i < NB_SCAN) ? blocksum[i] : 0;
    s[i] = v;
    __syncthreads();
    for (int off = 1; off < 512; off <<= 1) {
        int t = (i >= off) ? s[i - off] : 0;
        __syncthreads();
        s[i] += t;
        __syncthreads();
    }
    if (i < NB_SCAN) blockoff[i] = s[i] - v;
}

__global__ __launch_bounds__(256) void k_scan3(const int* __restrict__ deg,
                                               const int* __restrict__ blockoff,
                                               int* __restrict__ offsets,
                                               int* __restrict__ cursorF) {
    __shared__ int s[256];
    int i = blockIdx.x * 256 + threadIdx.x;
    int v = (i < N_NODES) ? deg[i] : 0;
    s[threadIdx.x] = v;
    __syncthreads();
    for (int off = 1; off < 256; off <<= 1) {
        int t = (threadIdx.x >= off) ? s[threadIdx.x - off] : 0;
        __syncthreads();
        s[threadIdx.x] += t;
        __syncthreads();
    }
    if (i < N_NODES) {
        int excl = blockoff[blockIdx.x] + s[threadIdx.x] - v;
        offsets[i] = excl;
        cursorF[i] = excl;
    }
}

// -------- Pass A: counting-sort 1024 edges by coarse bucket in LDS, --------
// -------- write contiguous per-bucket int4 runs into staged area   --------
__global__ __launch_bounds__(1024) void k_binA(
    const int* __restrict__ src,
    const int* __restrict__ dst,
    const float* __restrict__ ew,
    int* __restrict__ bucket_cursor,
    int4* __restrict__ staged) {
    __shared__ int cnt[NBKT];
    __shared__ int lstart[NBKT];
    __shared__ int gbase[NBKT];
    __shared__ int scanbuf[128];
    __shared__ int4 ebuf[1024];
    int tid = threadIdx.x;
    int e = blockIdx.x * 1024 + tid;

    if (tid < NBKT) cnt[tid] = 0;
    __syncthreads();

    int d = 0, s = 0, b = 0, rank = 0, wbits = 0;
    bool valid = (e < E_EDGES);
    if (valid) {
        d = dst[e]; s = src[e]; wbits = __float_as_int(ew[e]);
        b = d >> BSHIFT;
        rank = atomicAdd(&cnt[b], 1);
    }
    __syncthreads();

    if (tid < 128) scanbuf[tid] = (tid < NBKT) ? cnt[tid] : 0;
    __syncthreads();
    for (int off = 1; off < 128; off <<= 1) {
        int t = 0;
        if (tid < 128 && tid >= off) t = scanbuf[tid - off];
        __syncthreads();
        if (tid < 128) scanbuf[tid] += t;
        __syncthreads();
    }
    if (tid < NBKT) {
        lstart[tid] = scanbuf[tid] - cnt[tid];
        gbase[tid]  = atomicAdd(&bucket_cursor[tid], cnt[tid]);
    }
    __syncthreads();
    int total = scanbuf[NBKT - 1];

    if (valid)
        ebuf[lstart[b] + rank] = make_int4(d, s, wbits, 0);
    __syncthreads();

    if (tid < total) {
        int4 ev = ebuf[tid];
        int bb = ev.x >> BSHIFT;
        int gpos = gbase[bb] + (tid - lstart[bb]);
        if (gpos < BCAP)
            staged[(size_t)bb * BCAP + gpos] = ev;
    }
}

// -------- Pass B: one block per bucket; fine scatter into L2-local region --
__global__ __launch_bounds__(1024) void k_binB(
    const int* __restrict__ bucket_cursor,
    const int4* __restrict__ staged,
    int* __restrict__ cursorF,
    int2* __restrict__ csr8) {
    int b = blockIdx.x;
    int count = bucket_cursor[b];
    if (count > BCAP) count = BCAP;
    const int4* sp = staged + (size_t)b * BCAP;
    for (int i = threadIdx.x; i < count; i += 1024) {
        int4 ev = sp[i];
        int pos = atomicAdd(&cursorF[ev.x], 1);
        csr8[pos] = make_int2(ev.y, ev.z);
    }
}

// -------- Layer 1 fused: gather-mean + root + relu + project to 5+5 --------
__global__ __launch_bounds__(256) void k_layer1(
    const int* __restrict__ offsets,
    const int* __restrict__ deg,
    const int2* __restrict__ csr8,
    const float* __restrict__ xrel,
    const float* __restrict__ xroot,
    const float* __restrict__ Wrel2,
    const float* __restrict__ Wroot2,
    const float* __restrict__ b2,
    float* __restrict__ h2rel,
    float* __restrict__ h2root) {
    int node = blockIdx.x * 8 + (threadIdx.x >> 5);
    int lane = threadIdx.x & 31;
    int beg = offsets[node];
    int dg  = deg[node];
    int end = beg + dg;

    float acc = 0.f;
    int i = beg;
    for (; i + 4 <= end; i += 4) {
        int2 e0 = csr8[i];
        int2 e1 = csr8[i + 1];
        int2 e2 = csr8[i + 2];
        int2 e3 = csr8[i + 3];
        float v0 = xrel[(size_t)e0.x * H_MID + lane];
        float v1 = xrel[(size_t)e1.x * H_MID + lane];
        float v2 = xrel[(size_t)e2.x * H_MID + lane];
        float v3 = xrel[(size_t)e3.x * H_MID + lane];
        acc += v0 * __int_as_float(e0.y) + v1 * __int_as_float(e1.y)
             + v2 * __int_as_float(e2.y) + v3 * __int_as_float(e3.y);
    }
    for (; i < end; ++i) {
        int2 e0 = csr8[i];
        acc += xrel[(size_t)e0.x * H_MID + lane] * __int_as_float(e0.y);
    }

    float inv = 1.0f / fmaxf((float)dg, 1.0f);
    float h = fmaxf(acc * inv + xroot[(size_t)node * H_MID + lane], 0.f);

    float p[2 * C_OUT];
    #pragma unroll
    for (int j = 0; j < C_OUT; ++j) {
        p[j]         = h * Wrel2[lane * C_OUT + j];
        p[C_OUT + j] = h * Wroot2[lane * C_OUT + j];
    }
    #pragma unroll
    for (int m = 16; m > 0; m >>= 1) {
        #pragma unroll
        for (int j = 0; j < 2 * C_OUT; ++j)
            p[j] += __shfl_xor(p[j], m, 32);
    }
    if (lane == 0) {
        #pragma unroll
        for (int j = 0; j < C_OUT; ++j) {
            h2rel[(size_t)node * C_OUT + j]  = p[j];
            h2root[(size_t)node * C_OUT + j] = p[C_OUT + j] + b2[j];
        }
    }
}

// -------- Layer 2 + log_softmax fused: 32 nodes/block, 8 lanes/node --------
__global__ __launch_bounds__(256) void k_layer2(
    const int* __restrict__ offsets,
    const int* __restrict__ deg,
    const int2* __restrict__ csr8,
    const float* __restrict__ h2rel,
    const float* __restrict__ h2root,
    float* __restrict__ out) {
    int node = blockIdx.x * 32 + (threadIdx.x >> 3);
    int lane = threadIdx.x & 7;
    int beg = offsets[node];
    int dg  = deg[node];
    int end = beg + dg;

    float acc = 0.f;
    if (lane < C_OUT) {
        int i = beg;
        for (; i + 4 <= end; i += 4) {
            int s0 = csr8[i].x;
            int s1 = csr8[i + 1].x;
            int s2 = csr8[i + 2].x;
            int s3 = csr8[i + 3].x;
            float v0 = h2rel[(size_t)s0 * C_OUT + lane];
            float v1 = h2rel[(size_t)s1 * C_OUT + lane];
            float v2 = h2rel[(size_t)s2 * C_OUT + lane];
            float v3 = h2rel[(size_t)s3 * C_OUT + lane];
            acc += v0 + v1 + v2 + v3;
        }
        for (; i < end; ++i)
            acc += h2rel[(size_t)csr8[i].x * C_OUT + lane];
    }
    float inv = 1.0f / fmaxf((float)dg, 1.0f);
    float o = (lane < C_OUT)
                  ? acc * inv + h2root[(size_t)node * C_OUT + lane]
                  : -INFINITY;
    float m = o;
    #pragma unroll
    for (int dd = 4; dd > 0; dd >>= 1) m = fmaxf(m, __shfl_xor(m, dd, 8));
    float e = (lane < C_OUT) ? expf(o - m) : 0.f;
    float ssum = e;
    #pragma unroll
    for (int dd = 4; dd > 0; dd >>= 1) ssum += __shfl_xor(ssum, dd, 8);
    float lse = m + logf(ssum);
    if (lane < C_OUT)
        out[(size_t)node * C_OUT + lane] = o - lse;
}

extern "C" void kernel_launch(void* const* d_in, const int* in_sizes, int n_in,
                              void* d_out, int out_size, void* d_ws, size_t ws_size,
                              hipStream_t stream) {
    const float* x      = (const float*)d_in[0];
    const int*   ei     = (const int*)d_in[1];
    const float* ew     = (const float*)d_in[2];
    const float* Wrel1  = (const float*)d_in[3];
    const float* Wroot1 = (const float*)d_in[4];
    const float* b1     = (const float*)d_in[5];
    const float* Wrel2  = (const float*)d_in[6];
    const float* Wroot2 = (const float*)d_in[7];
    const float* b2     = (const float*)d_in[8];
    float* out = (float*)d_out;

    const int* src = ei;
    const int* dst = ei + E_EDGES;

    // Workspace layout. staged (98*17500 int4 = 27.4MB) aliases
    // xrel..h2root (29.6MB) — dead before k1_proj/k_layer1 write there.
    char* ws = (char*)d_ws;
    int*   deg           = (int*)ws;                            // N
    int*   bucket_cursor = deg + N_NODES;                       // 128
    int*   offsets       = bucket_cursor + 128;                 // N
    int*   cursorF       = offsets + N_NODES;                   // N
    int*   blocksum      = cursorF + N_NODES;                   // 512
    int*   blockoff      = blocksum + 512;                      // 512
    int2*  csr8          = (int2*)(blockoff + 512);             // E int2
    float* xrel          = (float*)(csr8 + E_EDGES);            // 32N
    float* xroot         = xrel + (size_t)N_NODES * H_MID;      // 32N
    float* h2rel         = xroot + (size_t)N_NODES * H_MID;     // 5N
    float* h2root        = h2rel + (size_t)N_NODES * C_OUT;     // 5N
    int4*  staged        = (int4*)xrel;                         // alias (dead by k1_proj)

    // --- degree + offsets ---
    k_zero_int<<<(N_NODES + 128 + 255) / 256, 256, 0, stream>>>(deg, N_NODES + 128);
    k_hist<<<E_EDGES / 256, 256, 0, stream>>>(dst, deg);
    k_scan1<<<NB_SCAN, 256, 0, stream>>>(deg, blocksum);
    k_scan2<<<1, 512, 0, stream>>>(blocksum, blockoff);
    k_scan3<<<NB_SCAN, 256, 0, stream>>>(deg, blockoff, offsets, cursorF);

    // --- two-pass binned CSR build ---
    k_binA<<<(E_EDGES + 1023) / 1024, 1024, 0, stream>>>(src, dst, ew,
                                                         bucket_cursor, staged);
    k_binB<<<NBKT, 1024, 0, stream>>>(bucket_cursor, staged, cursorF, csr8);

    // --- dense projections (after staging is dead) ---
    k1_proj<<<(N_NODES + TN - 1) / TN, 1024, 0, stream>>>(x, Wrel1, Wroot1, b1,
                                                          xrel, xroot);

    // --- layer 1 fused gather + node update + layer-2 projections ---
    k_layer1<<<N_NODES / 8, 256, 0, stream>>>(offsets, deg, csr8,
                                              xrel, xroot, Wrel2, Wroot2, b2,
                                              h2rel, h2root);

    // --- layer 2 gather + log_softmax (fused) ---
    k_layer2<<<N_NODES / 32, 256, 0, stream>>>(offsets, deg, csr8,
                                               h2rel, h2root, out);
}

// Round 7
// 269.433 us; speedup vs baseline: 2.1795x; 1.3556x over previous
//
#include <hip/hip_runtime.h>
#include <math.h>

#define N_NODES 100000
#define E_EDGES 1600000
#define D_IN    128
#define H_MID   32
#define C_OUT   5
#define TN      64    // nodes per k1 block
#define XS_STRIDE 132 // 128 + 4 pad floats

#define NBKT   98     // coarse buckets: dst>>10, 99999>>10 = 97
#define BSHIFT 10
#define BNODES 1024   // nodes per bucket
#define BCAP   17500  // per-bucket staging capacity (mean 16384, +8.7 sigma)

// ---------------- K1: xrel = x @ W_rel1 ; xroot = x @ W_root1 + b1 ----------
// 1024 threads = 16 waves; each wave owns one 4-col group; lanes = 64 nodes.
// W panel wave-uniform -> s_load; x tile staged once to LDS.
__global__ __launch_bounds__(1024) void k1_proj(
    const float* __restrict__ x,
    const float* __restrict__ Wrel,
    const float* __restrict__ Wroot,
    const float* __restrict__ b1,
    float* __restrict__ xrel,
    float* __restrict__ xroot) {
    __shared__ float xs[TN * XS_STRIDE];
    int tid = threadIdx.x;
    int nodeBase = blockIdx.x * TN;

    #pragma unroll
    for (int t = tid; t < TN * 32; t += 1024) {
        int row = t >> 5;
        int k4  = t & 31;
        int node = nodeBase + row;
        float4 v = make_float4(0.f, 0.f, 0.f, 0.f);
        if (node < N_NODES)
            v = *(const float4*)(x + (size_t)node * D_IN + k4 * 4);
        *(float4*)(xs + row * XS_STRIDE + k4 * 4) = v;
    }
    __syncthreads();

    int lane = tid & 63;
    int colgrp = __builtin_amdgcn_readfirstlane(tid >> 6);  // 0..15
    bool isRel = (colgrp < 8);
    int col = (isRel ? colgrp : colgrp - 8) * 4;
    const float* Wb = (isRel ? Wrel : Wroot) + col;
    const float* xr = xs + lane * XS_STRIDE;

    float4 acc = make_float4(0.f, 0.f, 0.f, 0.f);
    #pragma unroll 8
    for (int k4 = 0; k4 < D_IN / 4; ++k4) {
        float4 xv = *(const float4*)(xr + k4 * 4);
        const float* w0 = Wb + (k4 * 4) * H_MID;
        float4 wa = *(const float4*)(w0);
        float4 wb = *(const float4*)(w0 + H_MID);
        float4 wc = *(const float4*)(w0 + 2 * H_MID);
        float4 wd = *(const float4*)(w0 + 3 * H_MID);
        acc.x += xv.x * wa.x + xv.y * wb.x + xv.z * wc.x + xv.w * wd.x;
        acc.y += xv.x * wa.y + xv.y * wb.y + xv.z * wc.y + xv.w * wd.y;
        acc.z += xv.x * wa.z + xv.y * wb.z + xv.z * wc.z + xv.w * wd.z;
        acc.w += xv.x * wa.w + xv.y * wb.w + xv.z * wc.w + xv.w * wd.w;
    }

    int node = nodeBase + lane;
    if (node < N_NODES) {
        if (isRel) {
            *(float4*)(xrel + (size_t)node * H_MID + col) = acc;
        } else {
            acc.x += b1[col + 0]; acc.y += b1[col + 1];
            acc.z += b1[col + 2]; acc.w += b1[col + 3];
            *(float4*)(xroot + (size_t)node * H_MID + col) = acc;
        }
    }
}

// ---------------- tiny zero (bucket counters) ----------------
__global__ void k_zero_small(int* __restrict__ p, int n) {
    int i = threadIdx.x;
    if (i < n) p[i] = 0;
}

// -------- Pass A: counting-sort 1024 edges by coarse bucket in LDS --------
__global__ __launch_bounds__(1024) void k_binA(
    const int* __restrict__ src,
    const int* __restrict__ dst,
    const float* __restrict__ ew,
    int* __restrict__ bucket_cursor,
    int4* __restrict__ staged) {
    __shared__ int cnt[NBKT];
    __shared__ int lstart[NBKT];
    __shared__ int gbase[NBKT];
    __shared__ int scanbuf[128];
    __shared__ int4 ebuf[1024];
    int tid = threadIdx.x;
    int e = blockIdx.x * 1024 + tid;

    if (tid < NBKT) cnt[tid] = 0;
    __syncthreads();

    int d = 0, s = 0, b = 0, rank = 0, wbits = 0;
    bool valid = (e < E_EDGES);
    if (valid) {
        d = dst[e]; s = src[e]; wbits = __float_as_int(ew[e]);
        b = d >> BSHIFT;
        rank = atomicAdd(&cnt[b], 1);
    }
    __syncthreads();

    if (tid < 128) scanbuf[tid] = (tid < NBKT) ? cnt[tid] : 0;
    __syncthreads();
    for (int off = 1; off < 128; off <<= 1) {
        int t = 0;
        if (tid < 128 && tid >= off) t = scanbuf[tid - off];
        __syncthreads();
        if (tid < 128) scanbuf[tid] += t;
        __syncthreads();
    }
    if (tid < NBKT) {
        lstart[tid] = scanbuf[tid] - cnt[tid];
        gbase[tid]  = atomicAdd(&bucket_cursor[tid], cnt[tid]);
    }
    __syncthreads();
    int total = scanbuf[NBKT - 1];

    if (valid)
        ebuf[lstart[b] + rank] = make_int4(d, s, wbits, 0);
    __syncthreads();

    if (tid < total) {
        int4 ev = ebuf[tid];
        int bb = ev.x >> BSHIFT;
        int gpos = gbase[bb] + (tid - lstart[bb]);
        if (gpos < BCAP)
            staged[(size_t)bb * BCAP + gpos] = ev;
    }
}

// -------- exclusive scan of the 98 bucket counts -> bucket_base ----------
__global__ void k_bktscan(const int* __restrict__ bucket_cursor,
                          int* __restrict__ bucket_base) {
    __shared__ int s[128];
    int i = threadIdx.x;
    int c = (i < NBKT) ? bucket_cursor[i] : 0;
    int v = (c > BCAP) ? BCAP : c;
    s[i] = v;
    __syncthreads();
    for (int off = 1; off < 128; off <<= 1) {
        int t = (i >= off) ? s[i - off] : 0;
        __syncthreads();
        s[i] += t;
        __syncthreads();
    }
    if (i < NBKT) bucket_base[i] = s[i] - v;
}

// -------- Pass B: per-bucket LDS histogram + scan + L2-local scatter -------
// Writes deg/offsets coalesced AND builds the csr slice. One block/bucket.
__global__ __launch_bounds__(1024) void k_binB2(
    const int* __restrict__ bucket_cursor,
    const int* __restrict__ bucket_base,
    const int4* __restrict__ staged,
    int* __restrict__ deg,
    int* __restrict__ offsets,
    int2* __restrict__ csr8) {
    __shared__ int hist[BNODES];
    __shared__ int scanb[BNODES];
    __shared__ int cur[BNODES];
    int tid = threadIdx.x;
    int b = blockIdx.x;
    int count = bucket_cursor[b];
    if (count > BCAP) count = BCAP;
    int base = bucket_base[b];
    int nodeBase = b << BSHIFT;
    const int4* sp = staged + (size_t)b * BCAP;

    hist[tid] = 0;
    __syncthreads();

    // pass 1: local histogram (also pulls bucket's staged region into L2)
    for (int i = tid; i < count; i += 1024)
        atomicAdd(&hist[sp[i].x - nodeBase], 1);
    __syncthreads();

    // inclusive scan over 1024 bins
    int v = hist[tid];
    scanb[tid] = v;
    __syncthreads();
    for (int off = 1; off < BNODES; off <<= 1) {
        int t = (tid >= off) ? scanb[tid - off] : 0;
        __syncthreads();
        scanb[tid] += t;
        __syncthreads();
    }
    int excl = scanb[tid] - v;
    int node = nodeBase + tid;
    if (node < N_NODES) {
        deg[node]     = v;
        offsets[node] = base + excl;
    }
    cur[tid] = excl;
    __syncthreads();

    // pass 2: scatter into this bucket's contiguous csr slice (L2-resident)
    for (int i = tid; i < count; i += 1024) {
        int4 ev = sp[i];
        int pos = atomicAdd(&cur[ev.x - nodeBase], 1);
        csr8[base + pos] = make_int2(ev.y, ev.z);
    }
}

// -------- Layer 1 fused: gather-mean + root + relu + project to 5+5 --------
__global__ __launch_bounds__(256) void k_layer1(
    const int* __restrict__ offsets,
    const int* __restrict__ deg,
    const int2* __restrict__ csr8,
    const float* __restrict__ xrel,
    const float* __restrict__ xroot,
    const float* __restrict__ Wrel2,
    const float* __restrict__ Wroot2,
    const float* __restrict__ b2,
    float* __restrict__ h2rel,
    float* __restrict__ h2root) {
    int node = blockIdx.x * 8 + (threadIdx.x >> 5);
    int lane = threadIdx.x & 31;
    int beg = offsets[node];
    int dg  = deg[node];
    int end = beg + dg;

    float acc = 0.f;
    int i = beg;
    for (; i + 4 <= end; i += 4) {
        int2 e0 = csr8[i];
        int2 e1 = csr8[i + 1];
        int2 e2 = csr8[i + 2];
        int2 e3 = csr8[i + 3];
        float v0 = xrel[(size_t)e0.x * H_MID + lane];
        float v1 = xrel[(size_t)e1.x * H_MID + lane];
        float v2 = xrel[(size_t)e2.x * H_MID + lane];
        float v3 = xrel[(size_t)e3.x * H_MID + lane];
        acc += v0 * __int_as_float(e0.y) + v1 * __int_as_float(e1.y)
             + v2 * __int_as_float(e2.y) + v3 * __int_as_float(e3.y);
    }
    for (; i < end; ++i) {
        int2 e0 = csr8[i];
        acc += xrel[(size_t)e0.x * H_MID + lane] * __int_as_float(e0.y);
    }

    float inv = 1.0f / fmaxf((float)dg, 1.0f);
    float h = fmaxf(acc * inv + xroot[(size_t)node * H_MID + lane], 0.f);

    float p[2 * C_OUT];
    #pragma unroll
    for (int j = 0; j < C_OUT; ++j) {
        p[j]         = h * Wrel2[lane * C_OUT + j];
        p[C_OUT + j] = h * Wroot2[lane * C_OUT + j];
    }
    #pragma unroll
    for (int m = 16; m > 0; m >>= 1) {
        #pragma unroll
        for (int j = 0; j < 2 * C_OUT; ++j)
            p[j] += __shfl_xor(p[j], m, 32);
    }
    if (lane == 0) {
        #pragma unroll
        for (int j = 0; j < C_OUT; ++j) {
            h2rel[(size_t)node * C_OUT + j]  = p[j];
            h2root[(size_t)node * C_OUT + j] = p[C_OUT + j] + b2[j];
        }
    }
}

// -------- Layer 2 + log_softmax fused: 32 nodes/block, 8 lanes/node --------
__global__ __launch_bounds__(256) void k_layer2(
    const int* __restrict__ offsets,
    const int* __restrict__ deg,
    const int2* __restrict__ csr8,
    const float* __restrict__ h2rel,
    const float* __restrict__ h2root,
    float* __restrict__ out) {
    int node = blockIdx.x * 32 + (threadIdx.x >> 3);
    int lane = threadIdx.x & 7;
    int beg = offsets[node];
    int dg  = deg[node];
    int end = beg + dg;

    float acc = 0.f;
    if (lane < C_OUT) {
        int i = beg;
        for (; i + 4 <= end; i += 4) {
            int s0 = csr8[i].x;
            int s1 = csr8[i + 1].x;
            int s2 = csr8[i + 2].x;
            int s3 = csr8[i + 3].x;
            float v0 = h2rel[(size_t)s0 * C_OUT + lane];
            float v1 = h2rel[(size_t)s1 * C_OUT + lane];
            float v2 = h2rel[(size_t)s2 * C_OUT + lane];
            float v3 = h2rel[(size_t)s3 * C_OUT + lane];
            acc += v0 + v1 + v2 + v3;
        }
        for (; i < end; ++i)
            acc += h2rel[(size_t)csr8[i].x * C_OUT + lane];
    }
    float inv = 1.0f / fmaxf((float)dg, 1.0f);
    float o = (lane < C_OUT)
                  ? acc * inv + h2root[(size_t)node * C_OUT + lane]
                  : -INFINITY;
    float m = o;
    #pragma unroll
    for (int dd = 4; dd > 0; dd >>= 1) m = fmaxf(m, __shfl_xor(m, dd, 8));
    float e = (lane < C_OUT) ? expf(o - m) : 0.f;
    float ssum = e;
    #pragma unroll
    for (int dd = 4; dd > 0; dd >>= 1) ssum += __shfl_xor(ssum, dd, 8);
    float lse = m + logf(ssum);
    if (lane < C_OUT)
        out[(size_t)node * C_OUT + lane] = o - lse;
}

extern "C" void kernel_launch(void* const* d_in, const int* in_sizes, int n_in,
                              void* d_out, int out_size, void* d_ws, size_t ws_size,
                              hipStream_t stream) {
    const float* x      = (const float*)d_in[0];
    const int*   ei     = (const int*)d_in[1];
    const float* ew     = (const float*)d_in[2];
    const float* Wrel1  = (const float*)d_in[3];
    const float* Wroot1 = (const float*)d_in[4];
    const float* b1     = (const float*)d_in[5];
    const float* Wrel2  = (const float*)d_in[6];
    const float* Wroot2 = (const float*)d_in[7];
    const float* b2     = (const float*)d_in[8];
    float* out = (float*)d_out;

    const int* src = ei;
    const int* dst = ei + E_EDGES;

    // Workspace layout. staged (98*17500 int4 = 27.4MB) aliases
    // xrel..h2root (29.6MB) — dead before k1_proj writes there.
    char* ws = (char*)d_ws;
    int*   deg           = (int*)ws;                            // N
    int*   bucket_cursor = deg + N_NODES;                       // 128
    int*   bucket_base   = bucket_cursor + 128;                 // 128
    int*   offsets       = bucket_base + 128;                   // N
    int2*  csr8          = (int2*)(offsets + N_NODES);          // E int2
    float* xrel          = (float*)(csr8 + E_EDGES);            // 32N
    float* xroot         = xrel + (size_t)N_NODES * H_MID;      // 32N
    float* h2rel         = xroot + (size_t)N_NODES * H_MID;     // 5N
    float* h2root        = h2rel + (size_t)N_NODES * C_OUT;     // 5N
    int4*  staged        = (int4*)xrel;                         // alias

    // --- binned CSR build (no global histogram, no global scans) ---
    k_zero_small<<<1, 128, 0, stream>>>(bucket_cursor, 128);
    k_binA<<<(E_EDGES + 1023) / 1024, 1024, 0, stream>>>(src, dst, ew,
                                                         bucket_cursor, staged);
    k_bktscan<<<1, 128, 0, stream>>>(bucket_cursor, bucket_base);
    k_binB2<<<NBKT, 1024, 0, stream>>>(bucket_cursor, bucket_base, staged,
                                       deg, offsets, csr8);

    // --- dense projections (after staging is dead) ---
    k1_proj<<<(N_NODES + TN - 1) / TN, 1024, 0, stream>>>(x, Wrel1, Wroot1, b1,
                                                          xrel, xroot);

    // --- layer 1 fused gather + node update + layer-2 projections ---
    k_layer1<<<N_NODES / 8, 256, 0, stream>>>(offsets, deg, csr8,
                                              xrel, xroot, Wrel2, Wroot2, b2,
                                              h2rel, h2root);

    // --- layer 2 gather + log_softmax (fused) ---
    k_layer2<<<N_NODES / 32, 256, 0, stream>>>(offsets, deg, csr8,
                                               h2rel, h2root, out);
}

// Round 8
// 258.840 us; speedup vs baseline: 2.2687x; 1.0409x over previous
//
#include <hip/hip_runtime.h>
#include <math.h>

#define N_NODES 100000
#define E_EDGES 1600000
#define D_IN    128
#define H_MID   32
#define C_OUT   5
#define TN      64    // nodes per k1 block
#define XS_STRIDE 132 // 128 + 4 pad floats

#define NBKT   98     // coarse buckets: dst>>10, 99999>>10 = 97
#define BSHIFT 10
#define BNODES 1024   // nodes per bucket
#define BCAP   17500  // per-bucket staging capacity (mean 16384)
#define SRC_BITS 17
#define SRC_MASK 0x1FFFF

// round-to-nearest-even fp32 -> bf16 bits
__device__ inline unsigned f2bf(float f) {
    unsigned u = __float_as_uint(f);
    return (u + 0x7FFFu + ((u >> 16) & 1u)) >> 16;
}

// ---------------- K1: xrel(bf16) = x @ W_rel1 ; xroot = x @ W_root1 + b1 ----
// 1024 threads = 16 waves; each wave owns one 4-col group; lanes = 64 nodes.
__global__ __launch_bounds__(1024) void k1_proj(
    const float* __restrict__ x,
    const float* __restrict__ Wrel,
    const float* __restrict__ Wroot,
    const float* __restrict__ b1,
    unsigned short* __restrict__ xrelh,
    float* __restrict__ xroot) {
    __shared__ float xs[TN * XS_STRIDE];
    int tid = threadIdx.x;
    int nodeBase = blockIdx.x * TN;

    #pragma unroll
    for (int t = tid; t < TN * 32; t += 1024) {
        int row = t >> 5;
        int k4  = t & 31;
        int node = nodeBase + row;
        float4 v = make_float4(0.f, 0.f, 0.f, 0.f);
        if (node < N_NODES)
            v = *(const float4*)(x + (size_t)node * D_IN + k4 * 4);
        *(float4*)(xs + row * XS_STRIDE + k4 * 4) = v;
    }
    __syncthreads();

    int lane = tid & 63;
    int colgrp = __builtin_amdgcn_readfirstlane(tid >> 6);  // 0..15
    bool isRel = (colgrp < 8);
    int col = (isRel ? colgrp : colgrp - 8) * 4;
    const float* Wb = (isRel ? Wrel : Wroot) + col;
    const float* xr = xs + lane * XS_STRIDE;

    float4 acc = make_float4(0.f, 0.f, 0.f, 0.f);
    #pragma unroll 8
    for (int k4 = 0; k4 < D_IN / 4; ++k4) {
        float4 xv = *(const float4*)(xr + k4 * 4);
        const float* w0 = Wb + (k4 * 4) * H_MID;
        float4 wa = *(const float4*)(w0);
        float4 wb = *(const float4*)(w0 + H_MID);
        float4 wc = *(const float4*)(w0 + 2 * H_MID);
        float4 wd = *(const float4*)(w0 + 3 * H_MID);
        acc.x += xv.x * wa.x + xv.y * wb.x + xv.z * wc.x + xv.w * wd.x;
        acc.y += xv.x * wa.y + xv.y * wb.y + xv.z * wc.y + xv.w * wd.y;
        acc.z += xv.x * wa.z + xv.y * wb.z + xv.z * wc.z + xv.w * wd.z;
        acc.w += xv.x * wa.w + xv.y * wb.w + xv.z * wc.w + xv.w * wd.w;
    }

    int node = nodeBase + lane;
    if (node < N_NODES) {
        if (isRel) {
            unsigned p0 = f2bf(acc.x) | (f2bf(acc.y) << 16);
            unsigned p1 = f2bf(acc.z) | (f2bf(acc.w) << 16);
            *(uint2*)(xrelh + (size_t)node * H_MID + col) = make_uint2(p0, p1);
        } else {
            acc.x += b1[col + 0]; acc.y += b1[col + 1];
            acc.z += b1[col + 2]; acc.w += b1[col + 3];
            *(float4*)(xroot + (size_t)node * H_MID + col) = acc;
        }
    }
}

// ---------------- tiny zero (bucket counters) ----------------
__global__ void k_zero_small(int* __restrict__ p, int n) {
    int i = threadIdx.x;
    if (i < n) p[i] = 0;
}

// -------- Pass A: counting-sort 1024 edges by coarse bucket in LDS --------
// staged element: int2 { (dstLow10 << 17) | src17 , w_bits }  (8 B/edge)
__global__ __launch_bounds__(1024) void k_binA(
    const int* __restrict__ src,
    const int* __restrict__ dst,
    const float* __restrict__ ew,
    int* __restrict__ bucket_cursor,
    int2* __restrict__ staged) {
    __shared__ int cnt[NBKT];
    __shared__ int lstart[NBKT];
    __shared__ int gbase[NBKT];
    __shared__ int scanbuf[128];
    __shared__ int2 ebuf[1024];
    __shared__ short bbuf[1024];
    int tid = threadIdx.x;
    int e = blockIdx.x * 1024 + tid;

    if (tid < NBKT) cnt[tid] = 0;
    __syncthreads();

    int b = 0, rank = 0, packed = 0, wbits = 0;
    bool valid = (e < E_EDGES);
    if (valid) {
        int d = dst[e];
        int s = src[e];
        wbits = __float_as_int(ew[e]);
        b = d >> BSHIFT;
        packed = ((d & (BNODES - 1)) << SRC_BITS) | s;
        rank = atomicAdd(&cnt[b], 1);
    }
    __syncthreads();

    if (tid < 128) scanbuf[tid] = (tid < NBKT) ? cnt[tid] : 0;
    __syncthreads();
    for (int off = 1; off < 128; off <<= 1) {
        int t = 0;
        if (tid < 128 && tid >= off) t = scanbuf[tid - off];
        __syncthreads();
        if (tid < 128) scanbuf[tid] += t;
        __syncthreads();
    }
    if (tid < NBKT) {
        lstart[tid] = scanbuf[tid] - cnt[tid];
        gbase[tid]  = atomicAdd(&bucket_cursor[tid], cnt[tid]);
    }
    __syncthreads();
    int total = scanbuf[NBKT - 1];

    if (valid) {
        int slot = lstart[b] + rank;
        ebuf[slot] = make_int2(packed, wbits);
        bbuf[slot] = (short)b;
    }
    __syncthreads();

    if (tid < total) {
        int2 ev = ebuf[tid];
        int bb = bbuf[tid];
        int gpos = gbase[bb] + (tid - lstart[bb]);
        if (gpos < BCAP)
            staged[(size_t)bb * BCAP + gpos] = ev;
    }
}

// -------- exclusive scan of the 98 bucket counts -> bucket_base ----------
__global__ void k_bktscan(const int* __restrict__ bucket_cursor,
                          int* __restrict__ bucket_base) {
    __shared__ int s[128];
    int i = threadIdx.x;
    int c = (i < NBKT) ? bucket_cursor[i] : 0;
    int v = (c > BCAP) ? BCAP : c;
    s[i] = v;
    __syncthreads();
    for (int off = 1; off < 128; off <<= 1) {
        int t = (i >= off) ? s[i - off] : 0;
        __syncthreads();
        s[i] += t;
        __syncthreads();
    }
    if (i < NBKT) bucket_base[i] = s[i] - v;
}

// -------- Pass B: per-bucket LDS histogram + scan + L2-local scatter -------
__global__ __launch_bounds__(1024) void k_binB2(
    const int* __restrict__ bucket_cursor,
    const int* __restrict__ bucket_base,
    const int2* __restrict__ staged,
    int* __restrict__ deg,
    int* __restrict__ offsets,
    int2* __restrict__ csr8) {
    __shared__ int hist[BNODES];
    __shared__ int scanb[BNODES];
    __shared__ int cur[BNODES];
    int tid = threadIdx.x;
    int b = blockIdx.x;
    int count = bucket_cursor[b];
    if (count > BCAP) count = BCAP;
    int base = bucket_base[b];
    int nodeBase = b << BSHIFT;
    const int2* sp = staged + (size_t)b * BCAP;

    hist[tid] = 0;
    __syncthreads();

    for (int i = tid; i < count; i += 1024)
        atomicAdd(&hist[((unsigned)sp[i].x) >> SRC_BITS], 1);
    __syncthreads();

    int v = hist[tid];
    scanb[tid] = v;
    __syncthreads();
    for (int off = 1; off < BNODES; off <<= 1) {
        int t = (tid >= off) ? scanb[tid - off] : 0;
        __syncthreads();
        scanb[tid] += t;
        __syncthreads();
    }
    int excl = scanb[tid] - v;
    int node = nodeBase + tid;
    if (node < N_NODES) {
        deg[node]     = v;
        offsets[node] = base + excl;
    }
    cur[tid] = excl;
    __syncthreads();

    for (int i = tid; i < count; i += 1024) {
        int2 ev = sp[i];
        int local = ((unsigned)ev.x) >> SRC_BITS;
        int pos = atomicAdd(&cur[local], 1);
        csr8[base + pos] = make_int2(ev.x & SRC_MASK, ev.y);
    }
}

// -------- Layer 1 fused: bf16 gather-mean + root + relu + project ----------
// 16 nodes/block, 16 lanes/node, 2 columns per lane (bf16x2 loads).
__global__ __launch_bounds__(256) void k_layer1(
    const int* __restrict__ offsets,
    const int* __restrict__ deg,
    const int2* __restrict__ csr8,
    const unsigned short* __restrict__ xrelh,
    const float* __restrict__ xroot,
    const float* __restrict__ Wrel2,
    const float* __restrict__ Wroot2,
    const float* __restrict__ b2,
    float* __restrict__ h2rel,
    float* __restrict__ h2root) {
    int node = blockIdx.x * 16 + (threadIdx.x >> 4);
    int lane = threadIdx.x & 15;           // 2 cols: 2*lane, 2*lane+1
    int beg = offsets[node];
    int dg  = deg[node];
    int end = beg + dg;

    float acc0 = 0.f, acc1 = 0.f;
    int i = beg;
    for (; i + 4 <= end; i += 4) {
        int2 e0 = csr8[i];
        int2 e1 = csr8[i + 1];
        int2 e2 = csr8[i + 2];
        int2 e3 = csr8[i + 3];
        unsigned v0 = *(const unsigned*)(xrelh + (size_t)e0.x * H_MID + lane * 2);
        unsigned v1 = *(const unsigned*)(xrelh + (size_t)e1.x * H_MID + lane * 2);
        unsigned v2 = *(const unsigned*)(xrelh + (size_t)e2.x * H_MID + lane * 2);
        unsigned v3 = *(const unsigned*)(xrelh + (size_t)e3.x * H_MID + lane * 2);
        float w0 = __int_as_float(e0.y), w1 = __int_as_float(e1.y);
        float w2 = __int_as_float(e2.y), w3 = __int_as_float(e3.y);
        acc0 += __uint_as_float((v0 & 0xFFFFu) << 16) * w0
              + __uint_as_float((v1 & 0xFFFFu) << 16) * w1
              + __uint_as_float((v2 & 0xFFFFu) << 16) * w2
              + __uint_as_float((v3 & 0xFFFFu) << 16) * w3;
        acc1 += __uint_as_float(v0 & 0xFFFF0000u) * w0
              + __uint_as_float(v1 & 0xFFFF0000u) * w1
              + __uint_as_float(v2 & 0xFFFF0000u) * w2
              + __uint_as_float(v3 & 0xFFFF0000u) * w3;
    }
    for (; i < end; ++i) {
        int2 e0 = csr8[i];
        unsigned v0 = *(const unsigned*)(xrelh + (size_t)e0.x * H_MID + lane * 2);
        float w0 = __int_as_float(e0.y);
        acc0 += __uint_as_float((v0 & 0xFFFFu) << 16) * w0;
        acc1 += __uint_as_float(v0 & 0xFFFF0000u) * w0;
    }

    float inv = 1.0f / fmaxf((float)dg, 1.0f);
    float2 rt = *(const float2*)(xroot + (size_t)node * H_MID + lane * 2);
    float h0 = fmaxf(acc0 * inv + rt.x, 0.f);
    float h1 = fmaxf(acc1 * inv + rt.y, 0.f);

    float p[2 * C_OUT];
    #pragma unroll
    for (int j = 0; j < C_OUT; ++j) {
        p[j]         = h0 * Wrel2[(2 * lane) * C_OUT + j]
                     + h1 * Wrel2[(2 * lane + 1) * C_OUT + j];
        p[C_OUT + j] = h0 * Wroot2[(2 * lane) * C_OUT + j]
                     + h1 * Wroot2[(2 * lane + 1) * C_OUT + j];
    }
    #pragma unroll
    for (int m = 8; m > 0; m >>= 1) {
        #pragma unroll
        for (int j = 0; j < 2 * C_OUT; ++j)
            p[j] += __shfl_xor(p[j], m, 16);
    }
    if (lane == 0) {
        #pragma unroll
        for (int j = 0; j < C_OUT; ++j) {
            h2rel[(size_t)node * C_OUT + j]  = p[j];
            h2root[(size_t)node * C_OUT + j] = p[C_OUT + j] + b2[j];
        }
    }
}

// -------- Layer 2 + log_softmax fused: 32 nodes/block, 8 lanes/node --------
__global__ __launch_bounds__(256) void k_layer2(
    const int* __restrict__ offsets,
    const int* __restrict__ deg,
    const int2* __restrict__ csr8,
    const float* __restrict__ h2rel,
    const float* __restrict__ h2root,
    float* __restrict__ out) {
    int node = blockIdx.x * 32 + (threadIdx.x >> 3);
    int lane = threadIdx.x & 7;
    int beg = offsets[node];
    int dg  = deg[node];
    int end = beg + dg;

    float acc = 0.f;
    if (lane < C_OUT) {
        int i = beg;
        for (; i + 4 <= end; i += 4) {
            int s0 = csr8[i].x;
            int s1 = csr8[i + 1].x;
            int s2 = csr8[i + 2].x;
            int s3 = csr8[i + 3].x;
            float v0 = h2rel[(size_t)s0 * C_OUT + lane];
            float v1 = h2rel[(size_t)s1 * C_OUT + lane];
            float v2 = h2rel[(size_t)s2 * C_OUT + lane];
            float v3 = h2rel[(size_t)s3 * C_OUT + lane];
            acc += v0 + v1 + v2 + v3;
        }
        for (; i < end; ++i)
            acc += h2rel[(size_t)csr8[i].x * C_OUT + lane];
    }
    float inv = 1.0f / fmaxf((float)dg, 1.0f);
    float o = (lane < C_OUT)
                  ? acc * inv + h2root[(size_t)node * C_OUT + lane]
                  : -INFINITY;
    float m = o;
    #pragma unroll
    for (int dd = 4; dd > 0; dd >>= 1) m = fmaxf(m, __shfl_xor(m, dd, 8));
    float e = (lane < C_OUT) ? expf(o - m) : 0.f;
    float ssum = e;
    #pragma unroll
    for (int dd = 4; dd > 0; dd >>= 1) ssum += __shfl_xor(ssum, dd, 8);
    float lse = m + logf(ssum);
    if (lane < C_OUT)
        out[(size_t)node * C_OUT + lane] = o - lse;
}

extern "C" void kernel_launch(void* const* d_in, const int* in_sizes, int n_in,
                              void* d_out, int out_size, void* d_ws, size_t ws_size,
                              hipStream_t stream) {
    const float* x      = (const float*)d_in[0];
    const int*   ei     = (const int*)d_in[1];
    const float* ew     = (const float*)d_in[2];
    const float* Wrel1  = (const float*)d_in[3];
    const float* Wroot1 = (const float*)d_in[4];
    const float* b1     = (const float*)d_in[5];
    const float* Wrel2  = (const float*)d_in[6];
    const float* Wroot2 = (const float*)d_in[7];
    const float* b2     = (const float*)d_in[8];
    float* out = (float*)d_out;

    const int* src = ei;
    const int* dst = ei + E_EDGES;

    // Workspace (4B units). staged (98*17500 int2 = 13.7MB) aliases
    // xrelh+xroot (6.4+12.8=19.2MB) — dead before k1_proj writes there.
    char* ws = (char*)d_ws;
    int*   deg           = (int*)ws;                            // N
    int*   bucket_cursor = deg + N_NODES;                       // 128
    int*   bucket_base   = bucket_cursor + 128;                 // 128
    int*   offsets       = bucket_base + 128;                   // N
    int2*  csr8          = (int2*)(offsets + N_NODES);          // E int2
    unsigned short* xrelh = (unsigned short*)(csr8 + E_EDGES);  // 32N ushort
    float* xroot         = (float*)(xrelh + (size_t)N_NODES * H_MID); // 32N
    float* h2rel         = xroot + (size_t)N_NODES * H_MID;     // 5N
    float* h2root        = h2rel + (size_t)N_NODES * C_OUT;     // 5N
    int2*  staged        = (int2*)xrelh;                        // alias

    // --- binned CSR build ---
    k_zero_small<<<1, 128, 0, stream>>>(bucket_cursor, 128);
    k_binA<<<(E_EDGES + 1023) / 1024, 1024, 0, stream>>>(src, dst, ew,
                                                         bucket_cursor, staged);
    k_bktscan<<<1, 128, 0, stream>>>(bucket_cursor, bucket_base);
    k_binB2<<<NBKT, 1024, 0, stream>>>(bucket_cursor, bucket_base, staged,
                                       deg, offsets, csr8);

    // --- dense projections (after staging is dead) ---
    k1_proj<<<(N_NODES + TN - 1) / TN, 1024, 0, stream>>>(x, Wrel1, Wroot1, b1,
                                                          xrelh, xroot);

    // --- layer 1 fused gather + node update + layer-2 projections ---
    k_layer1<<<N_NODES / 16, 256, 0, stream>>>(offsets, deg, csr8,
                                               xrelh, xroot, Wrel2, Wroot2, b2,
                                               h2rel, h2root);

    // --- layer 2 gather + log_softmax (fused) ---
    k_layer2<<<N_NODES / 32, 256, 0, stream>>>(offsets, deg, csr8,
                                               h2rel, h2root, out);
}

// Round 9
// 243.562 us; speedup vs baseline: 2.4110x; 1.0627x over previous
//
#include <hip/hip_runtime.h>
#include <math.h>

#define N_NODES 100000
#define E_EDGES 1600000
#define D_IN    128
#define H_MID   32
#define C_OUT   5

#define NBKT   98     // coarse buckets: dst>>10, 99999>>10 = 97
#define BSHIFT 10
#define BNODES 1024   // nodes per bucket
#define BCAP   17500  // per-bucket staging capacity (mean 16384)
#define SRC_BITS 17
#define SRC_MASK 0x1FFFF

#define KP 136        // LDS k-stride in bf16 units (272 B; x16B aligned, spreads banks)

typedef __attribute__((ext_vector_type(8))) short bf16x8;
typedef __attribute__((ext_vector_type(4))) float f32x4;

// round-to-nearest-even fp32 -> bf16 bits
__device__ inline unsigned f2bf(float f) {
    unsigned u = __float_as_uint(f);
    return (u + 0x7FFFu + ((u >> 16) & 1u)) >> 16;
}

// ---------------- K1 (MFMA): [xrel|xroot] = x @ [Wrel|Wroot] ----------------
// 256 threads = 4 waves; block tile M=64 nodes, N=64 outputs, K=128.
// x tile + transposed W panel staged to LDS as bf16; 16 MFMA per wave.
__global__ __launch_bounds__(256) void k1_mfma(
    const float* __restrict__ x,
    const float* __restrict__ Wrel,
    const float* __restrict__ Wroot,
    const float* __restrict__ b1,
    unsigned short* __restrict__ xrelh,
    float* __restrict__ xroot) {
    __shared__ unsigned short xs[64 * KP];
    __shared__ unsigned short wt[64 * KP];
    int tid = threadIdx.x;
    int nodeBase = blockIdx.x * 64;

    // Stage W transposed: wt[n][k] = W[k][n]; n<32 rel, n>=32 root.
    #pragma unroll
    for (int it = 0; it < 32; ++it) {
        int idx = it * 256 + tid;          // over [k=128][n=64]
        int k = idx >> 6, n = idx & 63;
        float wvv = (n < 32) ? Wrel[k * H_MID + n] : Wroot[k * H_MID + (n - 32)];
        wt[n * KP + k] = (unsigned short)f2bf(wvv);
    }

    // Stage x tile as bf16: 64 rows x 64 float2 (coalesced 8B/lane).
    #pragma unroll
    for (int it = 0; it < 16; ++it) {
        int idx = it * 256 + tid;          // row*64 + kpair
        int row = idx >> 6, kp = idx & 63;
        int node = nodeBase + row;
        float2 v = make_float2(0.f, 0.f);
        if (node < N_NODES)
            v = *(const float2*)(x + (size_t)node * D_IN + kp * 2);
        unsigned pk = f2bf(v.x) | (f2bf(v.y) << 16);
        *(unsigned*)(xs + row * KP + kp * 2) = pk;
    }
    __syncthreads();

    int lane = tid & 63;
    int wv = tid >> 6;                     // wave 0..3 -> M rows [wv*16, +16)
    int m = lane & 15;
    int quad = lane >> 4;                  // 0..3

    f32x4 acc[4];
    #pragma unroll
    for (int nt = 0; nt < 4; ++nt) acc[nt] = (f32x4){0.f, 0.f, 0.f, 0.f};

    #pragma unroll
    for (int kk = 0; kk < 4; ++kk) {
        int k0 = kk * 32 + quad * 8;
        bf16x8 a = *(const bf16x8*)(xs + (wv * 16 + m) * KP + k0);
        #pragma unroll
        for (int nt = 0; nt < 4; ++nt) {
            bf16x8 b = *(const bf16x8*)(wt + (nt * 16 + m) * KP + k0);
            acc[nt] = __builtin_amdgcn_mfma_f32_16x16x32_bf16(a, b, acc[nt], 0, 0, 0);
        }
    }

    // Epilogue: C/D map col=lane&15, row=quad*4+reg (m89-verified).
    #pragma unroll
    for (int nt = 0; nt < 4; ++nt) {
        #pragma unroll
        for (int r = 0; r < 4; ++r) {
            int node = nodeBase + wv * 16 + quad * 4 + r;
            int colg = nt * 16 + m;
            if (node < N_NODES) {
                if (colg < H_MID) {
                    xrelh[(size_t)node * H_MID + colg] =
                        (unsigned short)f2bf(acc[nt][r]);
                } else {
                    int c = colg - H_MID;
                    xroot[(size_t)node * H_MID + c] = acc[nt][r] + b1[c];
                }
            }
        }
    }
}

// ---------------- tiny zero (bucket counters) ----------------
__global__ void k_zero_small(int* __restrict__ p, int n) {
    int i = threadIdx.x;
    if (i < n) p[i] = 0;
}

// -------- Pass A: counting-sort 1024 edges by coarse bucket in LDS --------
// staged element: int2 { (dstLow10 << 17) | src17 , w_bits }  (8 B/edge)
__global__ __launch_bounds__(1024) void k_binA(
    const int* __restrict__ src,
    const int* __restrict__ dst,
    const float* __restrict__ ew,
    int* __restrict__ bucket_cursor,
    int2* __restrict__ staged) {
    __shared__ int cnt[NBKT];
    __shared__ int lstart[NBKT];
    __shared__ int gbase[NBKT];
    __shared__ int scanbuf[128];
    __shared__ int2 ebuf[1024];
    __shared__ short bbuf[1024];
    int tid = threadIdx.x;
    int e = blockIdx.x * 1024 + tid;

    if (tid < NBKT) cnt[tid] = 0;
    __syncthreads();

    int b = 0, rank = 0, packed = 0, wbits = 0;
    bool valid = (e < E_EDGES);
    if (valid) {
        int d = dst[e];
        int s = src[e];
        wbits = __float_as_int(ew[e]);
        b = d >> BSHIFT;
        packed = ((d & (BNODES - 1)) << SRC_BITS) | s;
        rank = atomicAdd(&cnt[b], 1);
    }
    __syncthreads();

    if (tid < 128) scanbuf[tid] = (tid < NBKT) ? cnt[tid] : 0;
    __syncthreads();
    for (int off = 1; off < 128; off <<= 1) {
        int t = 0;
        if (tid < 128 && tid >= off) t = scanbuf[tid - off];
        __syncthreads();
        if (tid < 128) scanbuf[tid] += t;
        __syncthreads();
    }
    if (tid < NBKT) {
        lstart[tid] = scanbuf[tid] - cnt[tid];
        gbase[tid]  = atomicAdd(&bucket_cursor[tid], cnt[tid]);
    }
    __syncthreads();
    int total = scanbuf[NBKT - 1];

    if (valid) {
        int slot = lstart[b] + rank;
        ebuf[slot] = make_int2(packed, wbits);
        bbuf[slot] = (short)b;
    }
    __syncthreads();

    if (tid < total) {
        int2 ev = ebuf[tid];
        int bb = bbuf[tid];
        int gpos = gbase[bb] + (tid - lstart[bb]);
        if (gpos < BCAP)
            staged[(size_t)bb * BCAP + gpos] = ev;
    }
}

// -------- exclusive scan of the 98 bucket counts -> bucket_base ----------
__global__ void k_bktscan(const int* __restrict__ bucket_cursor,
                          int* __restrict__ bucket_base) {
    __shared__ int s[128];
    int i = threadIdx.x;
    int c = (i < NBKT) ? bucket_cursor[i] : 0;
    int v = (c > BCAP) ? BCAP : c;
    s[i] = v;
    __syncthreads();
    for (int off = 1; off < 128; off <<= 1) {
        int t = (i >= off) ? s[i - off] : 0;
        __syncthreads();
        s[i] += t;
        __syncthreads();
    }
    if (i < NBKT) bucket_base[i] = s[i] - v;
}

// -------- Pass B: per-bucket LDS histogram + scan + L2-local scatter -------
__global__ __launch_bounds__(1024) void k_binB2(
    const int* __restrict__ bucket_cursor,
    const int* __restrict__ bucket_base,
    const int2* __restrict__ staged,
    int* __restrict__ deg,
    int* __restrict__ offsets,
    int2* __restrict__ csr8) {
    __shared__ int hist[BNODES];
    __shared__ int scanb[BNODES];
    __shared__ int cur[BNODES];
    int tid = threadIdx.x;
    int b = blockIdx.x;
    int count = bucket_cursor[b];
    if (count > BCAP) count = BCAP;
    int base = bucket_base[b];
    int nodeBase = b << BSHIFT;
    const int2* sp = staged + (size_t)b * BCAP;

    hist[tid] = 0;
    __syncthreads();

    for (int i = tid; i < count; i += 1024)
        atomicAdd(&hist[((unsigned)sp[i].x) >> SRC_BITS], 1);
    __syncthreads();

    int v = hist[tid];
    scanb[tid] = v;
    __syncthreads();
    for (int off = 1; off < BNODES; off <<= 1) {
        int t = (tid >= off) ? scanb[tid - off] : 0;
        __syncthreads();
        scanb[tid] += t;
        __syncthreads();
    }
    int excl = scanb[tid] - v;
    int node = nodeBase + tid;
    if (node < N_NODES) {
        deg[node]     = v;
        offsets[node] = base + excl;
    }
    cur[tid] = excl;
    __syncthreads();

    for (int i = tid; i < count; i += 1024) {
        int2 ev = sp[i];
        int local = ((unsigned)ev.x) >> SRC_BITS;
        int pos = atomicAdd(&cur[local], 1);
        csr8[base + pos] = make_int2(ev.x & SRC_MASK, ev.y);
    }
}

// -------- Layer 1 fused: bf16 gather-mean + root + relu + project ----------
// 16 nodes/block, 16 lanes/node, 2 columns per lane (bf16x2 loads).
__global__ __launch_bounds__(256) void k_layer1(
    const int* __restrict__ offsets,
    const int* __restrict__ deg,
    const int2* __restrict__ csr8,
    const unsigned short* __restrict__ xrelh,
    const float* __restrict__ xroot,
    const float* __restrict__ Wrel2,
    const float* __restrict__ Wroot2,
    const float* __restrict__ b2,
    float* __restrict__ h2rel,
    float* __restrict__ h2root) {
    int node = blockIdx.x * 16 + (threadIdx.x >> 4);
    int lane = threadIdx.x & 15;           // 2 cols: 2*lane, 2*lane+1
    int beg = offsets[node];
    int dg  = deg[node];
    int end = beg + dg;

    float acc0 = 0.f, acc1 = 0.f;
    int i = beg;
    for (; i + 4 <= end; i += 4) {
        int2 e0 = csr8[i];
        int2 e1 = csr8[i + 1];
        int2 e2 = csr8[i + 2];
        int2 e3 = csr8[i + 3];
        unsigned v0 = *(const unsigned*)(xrelh + (size_t)e0.x * H_MID + lane * 2);
        unsigned v1 = *(const unsigned*)(xrelh + (size_t)e1.x * H_MID + lane * 2);
        unsigned v2 = *(const unsigned*)(xrelh + (size_t)e2.x * H_MID + lane * 2);
        unsigned v3 = *(const unsigned*)(xrelh + (size_t)e3.x * H_MID + lane * 2);
        float w0 = __int_as_float(e0.y), w1 = __int_as_float(e1.y);
        float w2 = __int_as_float(e2.y), w3 = __int_as_float(e3.y);
        acc0 += __uint_as_float((v0 & 0xFFFFu) << 16) * w0
              + __uint_as_float((v1 & 0xFFFFu) << 16) * w1
              + __uint_as_float((v2 & 0xFFFFu) << 16) * w2
              + __uint_as_float((v3 & 0xFFFFu) << 16) * w3;
        acc1 += __uint_as_float(v0 & 0xFFFF0000u) * w0
              + __uint_as_float(v1 & 0xFFFF0000u) * w1
              + __uint_as_float(v2 & 0xFFFF0000u) * w2
              + __uint_as_float(v3 & 0xFFFF0000u) * w3;
    }
    for (; i < end; ++i) {
        int2 e0 = csr8[i];
        unsigned v0 = *(const unsigned*)(xrelh + (size_t)e0.x * H_MID + lane * 2);
        float w0 = __int_as_float(e0.y);
        acc0 += __uint_as_float((v0 & 0xFFFFu) << 16) * w0;
        acc1 += __uint_as_float(v0 & 0xFFFF0000u) * w0;
    }

    float inv = 1.0f / fmaxf((float)dg, 1.0f);
    float2 rt = *(const float2*)(xroot + (size_t)node * H_MID + lane * 2);
    float h0 = fmaxf(acc0 * inv + rt.x, 0.f);
    float h1 = fmaxf(acc1 * inv + rt.y, 0.f);

    float p[2 * C_OUT];
    #pragma unroll
    for (int j = 0; j < C_OUT; ++j) {
        p[j]         = h0 * Wrel2[(2 * lane) * C_OUT + j]
                     + h1 * Wrel2[(2 * lane + 1) * C_OUT + j];
        p[C_OUT + j] = h0 * Wroot2[(2 * lane) * C_OUT + j]
                     + h1 * Wroot2[(2 * lane + 1) * C_OUT + j];
    }
    #pragma unroll
    for (int mm = 8; mm > 0; mm >>= 1) {
        #pragma unroll
        for (int j = 0; j < 2 * C_OUT; ++j)
            p[j] += __shfl_xor(p[j], mm, 16);
    }
    if (lane == 0) {
        #pragma unroll
        for (int j = 0; j < C_OUT; ++j) {
            h2rel[(size_t)node * C_OUT + j]  = p[j];
            h2root[(size_t)node * C_OUT + j] = p[C_OUT + j] + b2[j];
        }
    }
}

// -------- Layer 2 + log_softmax fused: 32 nodes/block, 8 lanes/node --------
__global__ __launch_bounds__(256) void k_layer2(
    const int* __restrict__ offsets,
    const int* __restrict__ deg,
    const int2* __restrict__ csr8,
    const float* __restrict__ h2rel,
    const float* __restrict__ h2root,
    float* __restrict__ out) {
    int node = blockIdx.x * 32 + (threadIdx.x >> 3);
    int lane = threadIdx.x & 7;
    int beg = offsets[node];
    int dg  = deg[node];
    int end = beg + dg;

    float acc = 0.f;
    if (lane < C_OUT) {
        int i = beg;
        for (; i + 4 <= end; i += 4) {
            int s0 = csr8[i].x;
            int s1 = csr8[i + 1].x;
            int s2 = csr8[i + 2].x;
            int s3 = csr8[i + 3].x;
            float v0 = h2rel[(size_t)s0 * C_OUT + lane];
            float v1 = h2rel[(size_t)s1 * C_OUT + lane];
            float v2 = h2rel[(size_t)s2 * C_OUT + lane];
            float v3 = h2rel[(size_t)s3 * C_OUT + lane];
            acc += v0 + v1 + v2 + v3;
        }
        for (; i < end; ++i)
            acc += h2rel[(size_t)csr8[i].x * C_OUT + lane];
    }
    float inv = 1.0f / fmaxf((float)dg, 1.0f);
    float o = (lane < C_OUT)
                  ? acc * inv + h2root[(size_t)node * C_OUT + lane]
                  : -INFINITY;
    float m = o;
    #pragma unroll
    for (int dd = 4; dd > 0; dd >>= 1) m = fmaxf(m, __shfl_xor(m, dd, 8));
    float e = (lane < C_OUT) ? expf(o - m) : 0.f;
    float ssum = e;
    #pragma unroll
    for (int dd = 4; dd > 0; dd >>= 1) ssum += __shfl_xor(ssum, dd, 8);
    float lse = m + logf(ssum);
    if (lane < C_OUT)
        out[(size_t)node * C_OUT + lane] = o - lse;
}

extern "C" void kernel_launch(void* const* d_in, const int* in_sizes, int n_in,
                              void* d_out, int out_size, void* d_ws, size_t ws_size,
                              hipStream_t stream) {
    const float* x      = (const float*)d_in[0];
    const int*   ei     = (const int*)d_in[1];
    const float* ew     = (const float*)d_in[2];
    const float* Wrel1  = (const float*)d_in[3];
    const float* Wroot1 = (const float*)d_in[4];
    const float* b1     = (const float*)d_in[5];
    const float* Wrel2  = (const float*)d_in[6];
    const float* Wroot2 = (const float*)d_in[7];
    const float* b2     = (const float*)d_in[8];
    float* out = (float*)d_out;

    const int* src = ei;
    const int* dst = ei + E_EDGES;

    // Workspace (4B units). staged (98*17500 int2 = 13.7MB) aliases
    // xrelh+xroot (6.4+12.8=19.2MB) — dead before k1_mfma writes there.
    char* ws = (char*)d_ws;
    int*   deg           = (int*)ws;                            // N
    int*   bucket_cursor = deg + N_NODES;                       // 128
    int*   bucket_base   = bucket_cursor + 128;                 // 128
    int*   offsets       = bucket_base + 128;                   // N
    int2*  csr8          = (int2*)(offsets + N_NODES);          // E int2
    unsigned short* xrelh = (unsigned short*)(csr8 + E_EDGES);  // 32N ushort
    float* xroot         = (float*)(xrelh + (size_t)N_NODES * H_MID); // 32N
    float* h2rel         = xroot + (size_t)N_NODES * H_MID;     // 5N
    float* h2root        = h2rel + (size_t)N_NODES * C_OUT;     // 5N
    int2*  staged        = (int2*)xrelh;                        // alias

    // --- binned CSR build ---
    k_zero_small<<<1, 128, 0, stream>>>(bucket_cursor, 128);
    k_binA<<<(E_EDGES + 1023) / 1024, 1024, 0, stream>>>(src, dst, ew,
                                                         bucket_cursor, staged);
    k_bktscan<<<1, 128, 0, stream>>>(bucket_cursor, bucket_base);
    k_binB2<<<NBKT, 1024, 0, stream>>>(bucket_cursor, bucket_base, staged,
                                       deg, offsets, csr8);

    // --- dense projections via MFMA (after staging is dead) ---
    k1_mfma<<<(N_NODES + 63) / 64, 256, 0, stream>>>(x, Wrel1, Wroot1, b1,
                                                     xrelh, xroot);

    // --- layer 1 fused gather + node update + layer-2 projections ---
    k_layer1<<<N_NODES / 16, 256, 0, stream>>>(offsets, deg, csr8,
                                               xrelh, xroot, Wrel2, Wroot2, b2,
                                               h2rel, h2root);

    // --- layer 2 gather + log_softmax (fused) ---
    k_layer2<<<N_NODES / 32, 256, 0, stream>>>(offsets, deg, csr8,
                                               h2rel, h2root, out);
}